// Round 1
// baseline (2872.367 us; speedup 1.0000x reference)
//
#include <hip/hip_runtime.h>
#include <hip/hip_bf16.h>

static constexpr int N_NODES = 100000;
static constexpr int N_EDGES = 1600000;
static constexpr int N_GRAPH = 2048;
static constexpr float BN_EPS_C = 1e-5f;

// ---------------- CSR build ----------------

__global__ __launch_bounds__(256) void k_hist(const int* __restrict__ dst, int* __restrict__ deg) {
    int i = blockIdx.x * 256 + threadIdx.x;
    if (i < N_EDGES) atomicAdd(&deg[dst[i]], 1);
}

__global__ __launch_bounds__(256) void k_scan_partial(const int* __restrict__ deg, int* __restrict__ part) {
    __shared__ int sw[4];
    int b = blockIdx.x, tid = threadIdx.x;
    int base = b * 1024;
    int s = 0;
#pragma unroll
    for (int r = 0; r < 4; ++r) {
        int i = base + r * 256 + tid;
        if (i < N_NODES) s += deg[i];
    }
#pragma unroll
    for (int off = 32; off > 0; off >>= 1) s += __shfl_down(s, off);
    if ((tid & 63) == 0) sw[tid >> 6] = s;
    __syncthreads();
    if (tid == 0) part[b] = sw[0] + sw[1] + sw[2] + sw[3];
}

__global__ __launch_bounds__(256) void k_scan_offsets(int* __restrict__ part, int nb) {
    __shared__ int sh[256];
    int tid = threadIdx.x;
    sh[tid] = (tid < nb) ? part[tid] : 0;
    __syncthreads();
    if (tid == 0) {
        int run = 0;
        for (int i = 0; i < nb; ++i) { int v = sh[i]; sh[i] = run; run += v; }
    }
    __syncthreads();
    if (tid < nb) part[tid] = sh[tid];
}

__global__ __launch_bounds__(256) void k_scan_final(const int* __restrict__ deg, const int* __restrict__ part,
                                                    int* __restrict__ row_ptr, int* __restrict__ cursor) {
    __shared__ int wsum[4];
    int b = blockIdx.x, tid = threadIdx.x;
    int lane = tid & 63, w = tid >> 6;
    int base = b * 1024 + tid * 4;
    int v[4];
#pragma unroll
    for (int r = 0; r < 4; ++r) {
        int i = base + r;
        v[r] = (i < N_NODES) ? deg[i] : 0;
    }
    int tsum = v[0] + v[1] + v[2] + v[3];
    int inc = tsum;
#pragma unroll
    for (int off = 1; off < 64; off <<= 1) {
        int t = __shfl_up(inc, off);
        if (lane >= off) inc += t;
    }
    if (lane == 63) wsum[w] = inc;
    __syncthreads();
    int woff = 0;
    for (int ww = 0; ww < w; ++ww) woff += wsum[ww];
    int run = part[b] + woff + (inc - tsum);
#pragma unroll
    for (int r = 0; r < 4; ++r) {
        int i = base + r;
        if (i < N_NODES) { row_ptr[i] = run; cursor[i] = run; }
        run += v[r];
    }
}

__global__ __launch_bounds__(256) void k_scatter(const int* __restrict__ src, const int* __restrict__ dst,
                                                 int* __restrict__ cursor, int* __restrict__ ssrc) {
    int i = blockIdx.x * 256 + threadIdx.x;
    if (i < N_EDGES) {
        int d = dst[i];
        int p = atomicAdd(&cursor[d], 1);
        ssrc[p] = src[i];
    }
}

// ---------------- GIN aggregation ----------------

// Layer-1 aggregation over x (64 features). One thread per (node, feat4): 16 lanes/node.
__global__ __launch_bounds__(256) void k_gather64(const float* __restrict__ x,
                                                  const int* __restrict__ row_ptr, const int* __restrict__ row_end,
                                                  const int* __restrict__ ssrc, float* __restrict__ out) {
    int idx = blockIdx.x * 256 + threadIdx.x;
    int node = idx >> 4;
    if (node >= N_NODES) return;
    int f = (idx & 15) * 4;
    float4 acc = *(const float4*)(x + (size_t)node * 64 + f);
    int e1 = row_end[node];
    for (int e = row_ptr[node]; e < e1; ++e) {
        int s = ssrc[e];
        float4 v = *(const float4*)(x + (size_t)s * 64 + f);
        acc.x += v.x; acc.y += v.y; acc.z += v.z; acc.w += v.w;
    }
    *(float4*)(out + (size_t)node * 64 + f) = acc;
}

// Layers 2-5 aggregation with previous layer's BN+ReLU applied on the fly.
__global__ __launch_bounds__(256) void k_gather_bn(const float* __restrict__ u, const float* __restrict__ stats,
                                                   const float* __restrict__ bng, const float* __restrict__ bnb,
                                                   const int* __restrict__ row_ptr, const int* __restrict__ row_end,
                                                   const int* __restrict__ ssrc, float* __restrict__ out) {
    int idx = blockIdx.x * 256 + threadIdx.x;
    int node = idx >> 3;
    if (node >= N_NODES) return;
    int f = (idx & 7) * 4;
    const float inv = 1.0f / (float)N_NODES;
    float4 s1 = *(const float4*)(stats + f);
    float4 s2 = *(const float4*)(stats + 32 + f);
    float4 g4 = *(const float4*)(bng + f);
    float4 b4 = *(const float4*)(bnb + f);
    float mux = s1.x * inv, muy = s1.y * inv, muz = s1.z * inv, muw = s1.w * inv;
    float scx = rsqrtf(s2.x * inv - mux * mux + BN_EPS_C) * g4.x;
    float scy = rsqrtf(s2.y * inv - muy * muy + BN_EPS_C) * g4.y;
    float scz = rsqrtf(s2.z * inv - muz * muz + BN_EPS_C) * g4.z;
    float scw = rsqrtf(s2.w * inv - muw * muw + BN_EPS_C) * g4.w;
    float shx = b4.x - mux * scx;
    float shy = b4.y - muy * scy;
    float shz = b4.z - muz * scz;
    float shw = b4.w - muw * scw;
    float4 uu = *(const float4*)(u + (size_t)node * 32 + f);
    float ax = fmaxf(uu.x * scx + shx, 0.f);
    float ay = fmaxf(uu.y * scy + shy, 0.f);
    float az = fmaxf(uu.z * scz + shz, 0.f);
    float aw = fmaxf(uu.w * scw + shw, 0.f);
    int e1 = row_end[node];
    for (int e = row_ptr[node]; e < e1; ++e) {
        int s = ssrc[e];
        float4 v = *(const float4*)(u + (size_t)s * 32 + f);
        ax += fmaxf(v.x * scx + shx, 0.f);
        ay += fmaxf(v.y * scy + shy, 0.f);
        az += fmaxf(v.z * scz + shz, 0.f);
        aw += fmaxf(v.w * scw + shw, 0.f);
    }
    float4 o; o.x = ax; o.y = ay; o.z = az; o.w = aw;
    *(float4*)(out + (size_t)node * 32 + f) = o;
}

// ---------------- node MLP + BN-stats ----------------

template <int K>
__global__ __launch_bounds__(256) void k_mlp_stats(const float* __restrict__ agg,
                                                   const float* __restrict__ Wa, const float* __restrict__ ba,
                                                   const float* __restrict__ Wb, const float* __restrict__ bb,
                                                   float* __restrict__ u, float* __restrict__ stats) {
    __shared__ float sWa[K * 32];
    __shared__ float sWb[1024];
    __shared__ float sba[32];
    __shared__ float sbb[32];
    int tid = threadIdx.x;
    for (int i = tid; i < K * 32; i += 256) sWa[i] = Wa[i];
    for (int i = tid; i < 1024; i += 256) sWb[i] = Wb[i];
    if (tid < 32) { sba[tid] = ba[tid]; sbb[tid] = bb[tid]; }
    __syncthreads();
    int node = blockIdx.x * 256 + tid;
    bool active = node < N_NODES;
    float t[32];
#pragma unroll
    for (int j = 0; j < 32; ++j) t[j] = sba[j];
    if (active) {
        const float* arow = agg + (size_t)node * K;
        for (int k = 0; k < K; k += 4) {
            float4 a4 = *(const float4*)(arow + k);
            float av[4] = {a4.x, a4.y, a4.z, a4.w};
#pragma unroll
            for (int kk = 0; kk < 4; ++kk) {
                float a = av[kk];
                const float4* wr = (const float4*)(sWa + (k + kk) * 32);
#pragma unroll
                for (int j4 = 0; j4 < 8; ++j4) {
                    float4 wv = wr[j4];
                    t[j4 * 4 + 0] = fmaf(a, wv.x, t[j4 * 4 + 0]);
                    t[j4 * 4 + 1] = fmaf(a, wv.y, t[j4 * 4 + 1]);
                    t[j4 * 4 + 2] = fmaf(a, wv.z, t[j4 * 4 + 2]);
                    t[j4 * 4 + 3] = fmaf(a, wv.w, t[j4 * 4 + 3]);
                }
            }
        }
    }
    float uu[32];
#pragma unroll
    for (int j = 0; j < 32; ++j) uu[j] = sbb[j];
    if (active) {
#pragma unroll
        for (int k = 0; k < 32; ++k) {
            float a = fmaxf(t[k], 0.f);
            const float4* wr = (const float4*)(sWb + k * 32);
#pragma unroll
            for (int j4 = 0; j4 < 8; ++j4) {
                float4 wv = wr[j4];
                uu[j4 * 4 + 0] = fmaf(a, wv.x, uu[j4 * 4 + 0]);
                uu[j4 * 4 + 1] = fmaf(a, wv.y, uu[j4 * 4 + 1]);
                uu[j4 * 4 + 2] = fmaf(a, wv.z, uu[j4 * 4 + 2]);
                uu[j4 * 4 + 3] = fmaf(a, wv.w, uu[j4 * 4 + 3]);
            }
        }
#pragma unroll
        for (int j4 = 0; j4 < 8; ++j4) {
            float4 o = make_float4(uu[j4 * 4 + 0], uu[j4 * 4 + 1], uu[j4 * 4 + 2], uu[j4 * 4 + 3]);
            *(float4*)(u + (size_t)node * 32 + j4 * 4) = o;
        }
    } else {
#pragma unroll
        for (int j = 0; j < 32; ++j) uu[j] = 0.f;
    }
    // wave-level column sums -> one atomic per wave per feature
#pragma unroll
    for (int j = 0; j < 32; ++j) {
        float v = uu[j];
        float v2 = v * v;
#pragma unroll
        for (int off = 32; off > 0; off >>= 1) {
            v += __shfl_down(v, off);
            v2 += __shfl_down(v2, off);
        }
        if ((tid & 63) == 0) {
            atomicAdd(&stats[j], v);
            atomicAdd(&stats[32 + j], v2);
        }
    }
}

// ---------------- layer-5 BN + graph pooling ----------------

__global__ __launch_bounds__(256) void k_bn_pool(const float* __restrict__ u, const float* __restrict__ stats,
                                                 const float* __restrict__ bng, const float* __restrict__ bnb,
                                                 const int* __restrict__ batch, float* __restrict__ pooled) {
    int idx = blockIdx.x * 256 + threadIdx.x;
    int node = idx >> 5;
    if (node >= N_NODES) return;
    int f = idx & 31;
    const float inv = 1.0f / (float)N_NODES;
    float mu = stats[f] * inv;
    float var = stats[32 + f] * inv - mu * mu;
    float sc = rsqrtf(var + BN_EPS_C) * bng[f];
    float sh = bnb[f] - mu * sc;
    float val = fmaxf(u[(size_t)node * 32 + f] * sc + sh, 0.f);
    atomicAdd(&pooled[(size_t)batch[node] * 32 + f], val);
}

// ---------------- generic head GEMM: C = act(A[M,K] @ B[K,Nc] + bias) ----------------
// M fixed by grid (blockIdx.x*64), all dims multiples of tile sizes by construction.

__global__ __launch_bounds__(256) void k_gemm(const float* __restrict__ A, const float* __restrict__ B,
                                              const float* __restrict__ bias, float* __restrict__ C,
                                              int Nc, int K, int ldc, int do_relu) {
    __shared__ float As[16][64];   // transposed A tile
    __shared__ float Bs[16][64];
    int tid = threadIdx.x;
    int tx = tid & 15, ty = tid >> 4;
    int bm = blockIdx.x * 64, bn = blockIdx.y * 64;
    float acc[4][4] = {{0.f}};
    int am = tid >> 2;            // 0..63
    int ak = (tid & 3) * 4;       // 0,4,8,12
    int bk = tid >> 4;            // 0..15
    int bn4 = (tid & 15) * 4;     // 0..60
    const float* Ap = A + (size_t)(bm + am) * K + ak;
    const float* Bp = B + (size_t)bk * Nc + bn + bn4;
    for (int k0 = 0; k0 < K; k0 += 16) {
        float4 av = *(const float4*)(Ap + k0);
        float4 bv = *(const float4*)(Bp + (size_t)k0 * Nc);
        As[ak + 0][am] = av.x;
        As[ak + 1][am] = av.y;
        As[ak + 2][am] = av.z;
        As[ak + 3][am] = av.w;
        *(float4*)&Bs[bk][bn4] = bv;
        __syncthreads();
#pragma unroll
        for (int k = 0; k < 16; ++k) {
            float4 a4 = *(const float4*)&As[k][ty * 4];
            float4 b4 = *(const float4*)&Bs[k][tx * 4];
            acc[0][0] = fmaf(a4.x, b4.x, acc[0][0]);
            acc[0][1] = fmaf(a4.x, b4.y, acc[0][1]);
            acc[0][2] = fmaf(a4.x, b4.z, acc[0][2]);
            acc[0][3] = fmaf(a4.x, b4.w, acc[0][3]);
            acc[1][0] = fmaf(a4.y, b4.x, acc[1][0]);
            acc[1][1] = fmaf(a4.y, b4.y, acc[1][1]);
            acc[1][2] = fmaf(a4.y, b4.z, acc[1][2]);
            acc[1][3] = fmaf(a4.y, b4.w, acc[1][3]);
            acc[2][0] = fmaf(a4.z, b4.x, acc[2][0]);
            acc[2][1] = fmaf(a4.z, b4.y, acc[2][1]);
            acc[2][2] = fmaf(a4.z, b4.z, acc[2][2]);
            acc[2][3] = fmaf(a4.z, b4.w, acc[2][3]);
            acc[3][0] = fmaf(a4.w, b4.x, acc[3][0]);
            acc[3][1] = fmaf(a4.w, b4.y, acc[3][1]);
            acc[3][2] = fmaf(a4.w, b4.z, acc[3][2]);
            acc[3][3] = fmaf(a4.w, b4.w, acc[3][3]);
        }
        __syncthreads();
    }
    float4 bi = *(const float4*)(bias + bn + tx * 4);
#pragma unroll
    for (int i = 0; i < 4; ++i) {
        float4 v;
        v.x = acc[i][0] + bi.x;
        v.y = acc[i][1] + bi.y;
        v.z = acc[i][2] + bi.z;
        v.w = acc[i][3] + bi.w;
        if (do_relu) {
            v.x = fmaxf(v.x, 0.f); v.y = fmaxf(v.y, 0.f);
            v.z = fmaxf(v.z, 0.f); v.w = fmaxf(v.w, 0.f);
        }
        *(float4*)(C + (size_t)(bm + ty * 4 + i) * ldc + bn + tx * 4) = v;
    }
}

// ---------------- final dot: out[g] = z2[g,:] . w + b ----------------

__global__ __launch_bounds__(256) void k_out(const float* __restrict__ z2, const float* __restrict__ w,
                                             const float* __restrict__ b, float* __restrict__ out) {
    int gid = blockIdx.x * 256 + threadIdx.x;
    int g = gid >> 6;
    int lane = threadIdx.x & 63;
    if (g >= N_GRAPH) return;
    float4 a = *(const float4*)(z2 + (size_t)g * 256 + lane * 4);
    float4 wv = *(const float4*)(w + lane * 4);
    float v = a.x * wv.x + a.y * wv.y + a.z * wv.z + a.w * wv.w;
#pragma unroll
    for (int off = 32; off > 0; off >>= 1) v += __shfl_down(v, off);
    if (lane == 0) out[g] = v + b[0];
}

// ---------------- launcher ----------------

extern "C" void kernel_launch(void* const* d_in, const int* in_sizes, int n_in,
                              void* d_out, int out_size, void* d_ws, size_t ws_size,
                              hipStream_t stream) {
    const float* x     = (const float*)d_in[0];
    const int*   eidx  = (const int*)d_in[1];
    const int*   batch = (const int*)d_in[2];
    const float* sf    = (const float*)d_in[3];
    const float* w1a   = (const float*)d_in[4];
    const float* b1a   = (const float*)d_in[5];
    const float* ws_a  = (const float*)d_in[6];
    const float* bs_a  = (const float*)d_in[7];
    const float* ws_b  = (const float*)d_in[8];
    const float* bs_b  = (const float*)d_in[9];
    const float* bn_g  = (const float*)d_in[10];
    const float* bn_b  = (const float*)d_in[11];
    const float* fcg_w = (const float*)d_in[12];
    const float* fcg_b = (const float*)d_in[13];
    const float* fs1_w = (const float*)d_in[14];
    const float* fs1_b = (const float*)d_in[15];
    const float* fs2_w = (const float*)d_in[16];
    const float* fs2_b = (const float*)d_in[17];
    const float* fc1_w = (const float*)d_in[18];
    const float* fc1_b = (const float*)d_in[19];
    const float* fc2_w = (const float*)d_in[20];
    const float* fc2_b = (const float*)d_in[21];
    const float* out_w = (const float*)d_in[22];
    const float* out_b = (const float*)d_in[23];
    float* dout = (float*)d_out;

    // workspace layout (~46.3 MB)
    float* agg     = (float*)d_ws;                       // N*64
    float* ubuf    = agg + (size_t)N_NODES * 64;         // N*32
    int*   ssrc    = (int*)(ubuf + (size_t)N_NODES * 32);// E
    int*   row_ptr = ssrc + N_EDGES;                     // N
    int*   cursor  = row_ptr + N_NODES;                  // N (after scatter: row end)
    int*   part    = cursor + N_NODES;                   // 128
    int*   deg     = part + 128;                         // N   -- zero region start
    float* stats   = (float*)(deg + N_NODES);            // 5*64
    float* pooled  = stats + 320;                        // G*32 -- zero region end
    // head buffers alias agg (dead by then)
    float* s1buf = agg;                                  // 2048*256
    float* zcat  = agg + 2048 * 256;                     // 2048*256 ([gfeat | s2])
    float* z1buf = zcat + 2048 * 256;                    // 2048*1024
    float* z2buf = z1buf + 2048 * 1024;                  // 2048*256

    size_t zero_bytes = ((size_t)N_NODES + 320 + 65536) * sizeof(int);
    hipMemsetAsync(deg, 0, zero_bytes, stream);

    const int* esrc = eidx;
    const int* edst = eidx + N_EDGES;
    int nb = (N_NODES + 1023) / 1024;  // 98

    k_hist<<<N_EDGES / 256, 256, 0, stream>>>(edst, deg);
    k_scan_partial<<<nb, 256, 0, stream>>>(deg, part);
    k_scan_offsets<<<1, 256, 0, stream>>>(part, nb);
    k_scan_final<<<nb, 256, 0, stream>>>(deg, part, row_ptr, cursor);
    k_scatter<<<N_EDGES / 256, 256, 0, stream>>>(esrc, edst, cursor, ssrc);

    // layer 1
    k_gather64<<<(N_NODES * 16) / 256, 256, 0, stream>>>(x, row_ptr, cursor, ssrc, agg);
    k_mlp_stats<64><<<(N_NODES + 255) / 256, 256, 0, stream>>>(agg, w1a, b1a, ws_b, bs_b, ubuf, stats);
    // layers 2-5
    for (int L = 1; L <= 4; ++L) {
        k_gather_bn<<<(N_NODES * 8) / 256, 256, 0, stream>>>(
            ubuf, stats + (L - 1) * 64, bn_g + (L - 1) * 32, bn_b + (L - 1) * 32,
            row_ptr, cursor, ssrc, agg);
        k_mlp_stats<32><<<(N_NODES + 255) / 256, 256, 0, stream>>>(
            agg, ws_a + (size_t)(L - 1) * 1024, bs_a + (L - 1) * 32,
            ws_b + (size_t)L * 1024, bs_b + L * 32, ubuf, stats + L * 64);
    }
    // layer-5 BN + pooling
    k_bn_pool<<<(N_NODES * 32) / 256, 256, 0, stream>>>(ubuf, stats + 256, bn_g + 128, bn_b + 128, batch, pooled);

    // head
    k_gemm<<<dim3(32, 2), 256, 0, stream>>>(pooled, fcg_w, fcg_b, zcat, 128, 32, 256, 1);        // gfeat -> z[:, :128]
    k_gemm<<<dim3(32, 4), 256, 0, stream>>>(sf, fs1_w, fs1_b, s1buf, 256, 512, 256, 1);          // s1
    k_gemm<<<dim3(32, 2), 256, 0, stream>>>(s1buf, fs2_w, fs2_b, zcat + 128, 128, 256, 256, 1);  // s2 -> z[:, 128:]
    k_gemm<<<dim3(32, 16), 256, 0, stream>>>(zcat, fc1_w, fc1_b, z1buf, 1024, 256, 1024, 1);     // fc1
    k_gemm<<<dim3(32, 4), 256, 0, stream>>>(z1buf, fc2_w, fc2_b, z2buf, 256, 1024, 256, 1);      // fc2
    k_out<<<512, 256, 0, stream>>>(z2buf, out_w, out_b, dout);
}

// Round 2
// 877.044 us; speedup vs baseline: 3.2751x; 3.2751x over previous
//
#include <hip/hip_runtime.h>
#include <hip/hip_bf16.h>

static constexpr int N_NODES = 100000;
static constexpr int N_EDGES = 1600000;
static constexpr int N_GRAPH = 2048;
static constexpr float BN_EPS_C = 1e-5f;

// ---------------- CSR build ----------------

__global__ __launch_bounds__(256) void k_hist(const int* __restrict__ dst, int* __restrict__ deg) {
    int i = blockIdx.x * 256 + threadIdx.x;
    if (i < N_EDGES) atomicAdd(&deg[dst[i]], 1);
}

__global__ __launch_bounds__(256) void k_scan_partial(const int* __restrict__ deg, int* __restrict__ part) {
    __shared__ int sw[4];
    int b = blockIdx.x, tid = threadIdx.x;
    int base = b * 1024;
    int s = 0;
#pragma unroll
    for (int r = 0; r < 4; ++r) {
        int i = base + r * 256 + tid;
        if (i < N_NODES) s += deg[i];
    }
#pragma unroll
    for (int off = 32; off > 0; off >>= 1) s += __shfl_down(s, off);
    if ((tid & 63) == 0) sw[tid >> 6] = s;
    __syncthreads();
    if (tid == 0) part[b] = sw[0] + sw[1] + sw[2] + sw[3];
}

__global__ __launch_bounds__(256) void k_scan_offsets(int* __restrict__ part, int nb) {
    __shared__ int sh[256];
    int tid = threadIdx.x;
    sh[tid] = (tid < nb) ? part[tid] : 0;
    __syncthreads();
    if (tid == 0) {
        int run = 0;
        for (int i = 0; i < nb; ++i) { int v = sh[i]; sh[i] = run; run += v; }
    }
    __syncthreads();
    if (tid < nb) part[tid] = sh[tid];
}

__global__ __launch_bounds__(256) void k_scan_final(const int* __restrict__ deg, const int* __restrict__ part,
                                                    int* __restrict__ row_ptr, int* __restrict__ cursor) {
    __shared__ int wsum[4];
    int b = blockIdx.x, tid = threadIdx.x;
    int lane = tid & 63, w = tid >> 6;
    int base = b * 1024 + tid * 4;
    int v[4];
#pragma unroll
    for (int r = 0; r < 4; ++r) {
        int i = base + r;
        v[r] = (i < N_NODES) ? deg[i] : 0;
    }
    int tsum = v[0] + v[1] + v[2] + v[3];
    int inc = tsum;
#pragma unroll
    for (int off = 1; off < 64; off <<= 1) {
        int t = __shfl_up(inc, off);
        if (lane >= off) inc += t;
    }
    if (lane == 63) wsum[w] = inc;
    __syncthreads();
    int woff = 0;
    for (int ww = 0; ww < w; ++ww) woff += wsum[ww];
    int run = part[b] + woff + (inc - tsum);
#pragma unroll
    for (int r = 0; r < 4; ++r) {
        int i = base + r;
        if (i < N_NODES) { row_ptr[i] = run; cursor[i] = run; }
        run += v[r];
    }
}

__global__ __launch_bounds__(256) void k_scatter(const int* __restrict__ src, const int* __restrict__ dst,
                                                 int* __restrict__ cursor, int* __restrict__ ssrc) {
    int i = blockIdx.x * 256 + threadIdx.x;
    if (i < N_EDGES) {
        int d = dst[i];
        int p = atomicAdd(&cursor[d], 1);
        ssrc[p] = src[i];
    }
}

// ---------------- GIN aggregation ----------------

// Layer-1 aggregation over x (64 features). 16 lanes/node, float4 each.
__global__ __launch_bounds__(256) void k_gather64(const float* __restrict__ x,
                                                  const int* __restrict__ row_ptr, const int* __restrict__ row_end,
                                                  const int* __restrict__ ssrc, float* __restrict__ out) {
    int idx = blockIdx.x * 256 + threadIdx.x;
    int node = idx >> 4;
    if (node >= N_NODES) return;
    int f = (idx & 15) * 4;
    float4 acc = *(const float4*)(x + (size_t)node * 64 + f);
    int e1 = row_end[node];
    for (int e = row_ptr[node]; e < e1; ++e) {
        int s = ssrc[e];
        float4 v = *(const float4*)(x + (size_t)s * 64 + f);
        acc.x += v.x; acc.y += v.y; acc.z += v.z; acc.w += v.w;
    }
    *(float4*)(out + (size_t)node * 64 + f) = acc;
}

// Layers 2-5 aggregation with previous layer's BN+ReLU applied on the fly.
__global__ __launch_bounds__(256) void k_gather_bn(const float* __restrict__ u, const float* __restrict__ stats,
                                                   const float* __restrict__ bng, const float* __restrict__ bnb,
                                                   const int* __restrict__ row_ptr, const int* __restrict__ row_end,
                                                   const int* __restrict__ ssrc, float* __restrict__ out) {
    int idx = blockIdx.x * 256 + threadIdx.x;
    int node = idx >> 3;
    if (node >= N_NODES) return;
    int f = (idx & 7) * 4;
    const float inv = 1.0f / (float)N_NODES;
    float4 s1 = *(const float4*)(stats + f);
    float4 s2 = *(const float4*)(stats + 32 + f);
    float4 g4 = *(const float4*)(bng + f);
    float4 b4 = *(const float4*)(bnb + f);
    float mux = s1.x * inv, muy = s1.y * inv, muz = s1.z * inv, muw = s1.w * inv;
    float scx = rsqrtf(s2.x * inv - mux * mux + BN_EPS_C) * g4.x;
    float scy = rsqrtf(s2.y * inv - muy * muy + BN_EPS_C) * g4.y;
    float scz = rsqrtf(s2.z * inv - muz * muz + BN_EPS_C) * g4.z;
    float scw = rsqrtf(s2.w * inv - muw * muw + BN_EPS_C) * g4.w;
    float shx = b4.x - mux * scx;
    float shy = b4.y - muy * scy;
    float shz = b4.z - muz * scz;
    float shw = b4.w - muw * scw;
    float4 uu = *(const float4*)(u + (size_t)node * 32 + f);
    float ax = fmaxf(uu.x * scx + shx, 0.f);
    float ay = fmaxf(uu.y * scy + shy, 0.f);
    float az = fmaxf(uu.z * scz + shz, 0.f);
    float aw = fmaxf(uu.w * scw + shw, 0.f);
    int e1 = row_end[node];
    for (int e = row_ptr[node]; e < e1; ++e) {
        int s = ssrc[e];
        float4 v = *(const float4*)(u + (size_t)s * 32 + f);
        ax += fmaxf(v.x * scx + shx, 0.f);
        ay += fmaxf(v.y * scy + shy, 0.f);
        az += fmaxf(v.z * scz + shz, 0.f);
        aw += fmaxf(v.w * scw + shw, 0.f);
    }
    float4 o; o.x = ax; o.y = ay; o.z = az; o.w = aw;
    *(float4*)(out + (size_t)node * 32 + f) = o;
}

// ---------------- node MLP + BN-stats ----------------
// Phase-split through LDS to keep live VGPRs ~40 (round-1 version spilled:
// VGPR_Count=44 with ~70 live accumulators -> scratch round-trips, 448us).

template <int K>
__global__ __launch_bounds__(256) void k_mlp_stats(const float* __restrict__ agg,
                                                   const float* __restrict__ Wa, const float* __restrict__ ba,
                                                   const float* __restrict__ Wb, const float* __restrict__ bb,
                                                   float* __restrict__ u, float* __restrict__ stats) {
    __shared__ float sWa[K * 32];
    __shared__ float sWb[1024];
    __shared__ float sba[32];
    __shared__ float sbb[32];
    __shared__ float tile[256][33];   // hidden vector t per node, padded
    __shared__ float bstats[64];
    int tid = threadIdx.x;
    for (int i = tid; i < K * 32; i += 256) sWa[i] = Wa[i];
    for (int i = tid; i < 1024; i += 256) sWb[i] = Wb[i];
    if (tid < 32) { sba[tid] = ba[tid]; sbb[tid] = bb[tid]; }
    if (tid < 64) bstats[tid] = 0.f;
    __syncthreads();
    int node = blockIdx.x * 256 + tid;
    bool active = node < N_NODES;

    // Phase A: t = relu(agg @ Wa + ba) -> LDS
    {
        float t[32];
#pragma unroll
        for (int j = 0; j < 32; ++j) t[j] = sba[j];
        if (active) {
            const float* arow = agg + (size_t)node * K;
            for (int k = 0; k < K; k += 4) {
                float4 a4 = *(const float4*)(arow + k);
                float av[4] = {a4.x, a4.y, a4.z, a4.w};
#pragma unroll
                for (int kk = 0; kk < 4; ++kk) {
                    float a = av[kk];
                    const float4* wr = (const float4*)(sWa + (k + kk) * 32);
#pragma unroll
                    for (int j4 = 0; j4 < 8; ++j4) {
                        float4 wv = wr[j4];
                        t[j4 * 4 + 0] = fmaf(a, wv.x, t[j4 * 4 + 0]);
                        t[j4 * 4 + 1] = fmaf(a, wv.y, t[j4 * 4 + 1]);
                        t[j4 * 4 + 2] = fmaf(a, wv.z, t[j4 * 4 + 2]);
                        t[j4 * 4 + 3] = fmaf(a, wv.w, t[j4 * 4 + 3]);
                    }
                }
            }
        }
#pragma unroll
        for (int j = 0; j < 32; ++j) tile[tid][j] = fmaxf(t[j], 0.f);
    }
    __syncthreads();

    // Phase B: uu = t @ Wb + bb
    float uu[32];
#pragma unroll
    for (int j = 0; j < 32; ++j) uu[j] = sbb[j];
#pragma unroll 4
    for (int k = 0; k < 32; ++k) {
        float a = tile[tid][k];
        const float4* wr = (const float4*)(sWb + k * 32);
#pragma unroll
        for (int j4 = 0; j4 < 8; ++j4) {
            float4 wv = wr[j4];
            uu[j4 * 4 + 0] = fmaf(a, wv.x, uu[j4 * 4 + 0]);
            uu[j4 * 4 + 1] = fmaf(a, wv.y, uu[j4 * 4 + 1]);
            uu[j4 * 4 + 2] = fmaf(a, wv.z, uu[j4 * 4 + 2]);
            uu[j4 * 4 + 3] = fmaf(a, wv.w, uu[j4 * 4 + 3]);
        }
    }
    if (active) {
#pragma unroll
        for (int j4 = 0; j4 < 8; ++j4) {
            float4 o = make_float4(uu[j4 * 4 + 0], uu[j4 * 4 + 1], uu[j4 * 4 + 2], uu[j4 * 4 + 3]);
            *(float4*)(u + (size_t)node * 32 + j4 * 4) = o;
        }
    } else {
#pragma unroll
        for (int j = 0; j < 32; ++j) uu[j] = 0.f;
    }

    // Stats: wave shuffle-reduce -> LDS block accumulate -> 64 global atomics/block
#pragma unroll
    for (int j = 0; j < 32; ++j) {
        float v = uu[j];
        float v2 = v * v;
#pragma unroll
        for (int off = 32; off > 0; off >>= 1) {
            v += __shfl_down(v, off);
            v2 += __shfl_down(v2, off);
        }
        if ((tid & 63) == 0) {
            atomicAdd(&bstats[j], v);
            atomicAdd(&bstats[32 + j], v2);
        }
    }
    __syncthreads();
    if (tid < 64) atomicAdd(&stats[tid], bstats[tid]);
}

// ---------------- layer-5 BN + graph pooling ----------------

__global__ __launch_bounds__(256) void k_bn_pool(const float* __restrict__ u, const float* __restrict__ stats,
                                                 const float* __restrict__ bng, const float* __restrict__ bnb,
                                                 const int* __restrict__ batch, float* __restrict__ pooled) {
    int idx = blockIdx.x * 256 + threadIdx.x;
    int node = idx >> 5;
    if (node >= N_NODES) return;
    int f = idx & 31;
    const float inv = 1.0f / (float)N_NODES;
    float mu = stats[f] * inv;
    float var = stats[32 + f] * inv - mu * mu;
    float sc = rsqrtf(var + BN_EPS_C) * bng[f];
    float sh = bnb[f] - mu * sc;
    float val = fmaxf(u[(size_t)node * 32 + f] * sc + sh, 0.f);
    atomicAdd(&pooled[(size_t)batch[node] * 32 + f], val);
}

// ---------------- generic head GEMM: C = act(A[M,K] @ B[K,Nc] + bias) ----------------

__global__ __launch_bounds__(256) void k_gemm(const float* __restrict__ A, const float* __restrict__ B,
                                              const float* __restrict__ bias, float* __restrict__ C,
                                              int Nc, int K, int ldc, int do_relu) {
    __shared__ float As[16][64];   // transposed A tile
    __shared__ float Bs[16][64];
    int tid = threadIdx.x;
    int tx = tid & 15, ty = tid >> 4;
    int bm = blockIdx.x * 64, bn = blockIdx.y * 64;
    float acc[4][4] = {{0.f}};
    int am = tid >> 2;
    int ak = (tid & 3) * 4;
    int bk = tid >> 4;
    int bn4 = (tid & 15) * 4;
    const float* Ap = A + (size_t)(bm + am) * K + ak;
    const float* Bp = B + (size_t)bk * Nc + bn + bn4;
    for (int k0 = 0; k0 < K; k0 += 16) {
        float4 av = *(const float4*)(Ap + k0);
        float4 bv = *(const float4*)(Bp + (size_t)k0 * Nc);
        As[ak + 0][am] = av.x;
        As[ak + 1][am] = av.y;
        As[ak + 2][am] = av.z;
        As[ak + 3][am] = av.w;
        *(float4*)&Bs[bk][bn4] = bv;
        __syncthreads();
#pragma unroll
        for (int k = 0; k < 16; ++k) {
            float4 a4 = *(const float4*)&As[k][ty * 4];
            float4 b4 = *(const float4*)&Bs[k][tx * 4];
            acc[0][0] = fmaf(a4.x, b4.x, acc[0][0]);
            acc[0][1] = fmaf(a4.x, b4.y, acc[0][1]);
            acc[0][2] = fmaf(a4.x, b4.z, acc[0][2]);
            acc[0][3] = fmaf(a4.x, b4.w, acc[0][3]);
            acc[1][0] = fmaf(a4.y, b4.x, acc[1][0]);
            acc[1][1] = fmaf(a4.y, b4.y, acc[1][1]);
            acc[1][2] = fmaf(a4.y, b4.z, acc[1][2]);
            acc[1][3] = fmaf(a4.y, b4.w, acc[1][3]);
            acc[2][0] = fmaf(a4.z, b4.x, acc[2][0]);
            acc[2][1] = fmaf(a4.z, b4.y, acc[2][1]);
            acc[2][2] = fmaf(a4.z, b4.z, acc[2][2]);
            acc[2][3] = fmaf(a4.z, b4.w, acc[2][3]);
            acc[3][0] = fmaf(a4.w, b4.x, acc[3][0]);
            acc[3][1] = fmaf(a4.w, b4.y, acc[3][1]);
            acc[3][2] = fmaf(a4.w, b4.z, acc[3][2]);
            acc[3][3] = fmaf(a4.w, b4.w, acc[3][3]);
        }
        __syncthreads();
    }
    float4 bi = *(const float4*)(bias + bn + tx * 4);
#pragma unroll
    for (int i = 0; i < 4; ++i) {
        float4 v;
        v.x = acc[i][0] + bi.x;
        v.y = acc[i][1] + bi.y;
        v.z = acc[i][2] + bi.z;
        v.w = acc[i][3] + bi.w;
        if (do_relu) {
            v.x = fmaxf(v.x, 0.f); v.y = fmaxf(v.y, 0.f);
            v.z = fmaxf(v.z, 0.f); v.w = fmaxf(v.w, 0.f);
        }
        *(float4*)(C + (size_t)(bm + ty * 4 + i) * ldc + bn + tx * 4) = v;
    }
}

// ---------------- final dot ----------------

__global__ __launch_bounds__(256) void k_out(const float* __restrict__ z2, const float* __restrict__ w,
                                             const float* __restrict__ b, float* __restrict__ out) {
    int gid = blockIdx.x * 256 + threadIdx.x;
    int g = gid >> 6;
    int lane = threadIdx.x & 63;
    if (g >= N_GRAPH) return;
    float4 a = *(const float4*)(z2 + (size_t)g * 256 + lane * 4);
    float4 wv = *(const float4*)(w + lane * 4);
    float v = a.x * wv.x + a.y * wv.y + a.z * wv.z + a.w * wv.w;
#pragma unroll
    for (int off = 32; off > 0; off >>= 1) v += __shfl_down(v, off);
    if (lane == 0) out[g] = v + b[0];
}

// ---------------- launcher ----------------

extern "C" void kernel_launch(void* const* d_in, const int* in_sizes, int n_in,
                              void* d_out, int out_size, void* d_ws, size_t ws_size,
                              hipStream_t stream) {
    const float* x     = (const float*)d_in[0];
    const int*   eidx  = (const int*)d_in[1];
    const int*   batch = (const int*)d_in[2];
    const float* sf    = (const float*)d_in[3];
    const float* w1a   = (const float*)d_in[4];
    const float* b1a   = (const float*)d_in[5];
    const float* ws_a  = (const float*)d_in[6];
    const float* bs_a  = (const float*)d_in[7];
    const float* ws_b  = (const float*)d_in[8];
    const float* bs_b  = (const float*)d_in[9];
    const float* bn_g  = (const float*)d_in[10];
    const float* bn_b  = (const float*)d_in[11];
    const float* fcg_w = (const float*)d_in[12];
    const float* fcg_b = (const float*)d_in[13];
    const float* fs1_w = (const float*)d_in[14];
    const float* fs1_b = (const float*)d_in[15];
    const float* fs2_w = (const float*)d_in[16];
    const float* fs2_b = (const float*)d_in[17];
    const float* fc1_w = (const float*)d_in[18];
    const float* fc1_b = (const float*)d_in[19];
    const float* fc2_w = (const float*)d_in[20];
    const float* fc2_b = (const float*)d_in[21];
    const float* out_w = (const float*)d_in[22];
    const float* out_b = (const float*)d_in[23];
    float* dout = (float*)d_out;

    float* agg     = (float*)d_ws;                       // N*64
    float* ubuf    = agg + (size_t)N_NODES * 64;         // N*32
    int*   ssrc    = (int*)(ubuf + (size_t)N_NODES * 32);// E
    int*   row_ptr = ssrc + N_EDGES;                     // N
    int*   cursor  = row_ptr + N_NODES;                  // N (after scatter: row end)
    int*   part    = cursor + N_NODES;                   // 128
    int*   deg     = part + 128;                         // N   -- zero region start
    float* stats   = (float*)(deg + N_NODES);            // 5*64
    float* pooled  = stats + 320;                        // G*32 -- zero region end
    float* s1buf = agg;                                  // 2048*256
    float* zcat  = agg + 2048 * 256;                     // 2048*256 ([gfeat | s2])
    float* z1buf = zcat + 2048 * 256;                    // 2048*1024
    float* z2buf = z1buf + 2048 * 1024;                  // 2048*256

    size_t zero_bytes = ((size_t)N_NODES + 320 + 65536) * sizeof(int);
    hipMemsetAsync(deg, 0, zero_bytes, stream);

    const int* esrc = eidx;
    const int* edst = eidx + N_EDGES;
    int nb = (N_NODES + 1023) / 1024;  // 98

    k_hist<<<N_EDGES / 256, 256, 0, stream>>>(edst, deg);
    k_scan_partial<<<nb, 256, 0, stream>>>(deg, part);
    k_scan_offsets<<<1, 256, 0, stream>>>(part, nb);
    k_scan_final<<<nb, 256, 0, stream>>>(deg, part, row_ptr, cursor);
    k_scatter<<<N_EDGES / 256, 256, 0, stream>>>(esrc, edst, cursor, ssrc);

    // layer 1
    k_gather64<<<(N_NODES * 16) / 256, 256, 0, stream>>>(x, row_ptr, cursor, ssrc, agg);
    k_mlp_stats<64><<<(N_NODES + 255) / 256, 256, 0, stream>>>(agg, w1a, b1a, ws_b, bs_b, ubuf, stats);
    // layers 2-5
    for (int L = 1; L <= 4; ++L) {
        k_gather_bn<<<(N_NODES * 8) / 256, 256, 0, stream>>>(
            ubuf, stats + (L - 1) * 64, bn_g + (L - 1) * 32, bn_b + (L - 1) * 32,
            row_ptr, cursor, ssrc, agg);
        k_mlp_stats<32><<<(N_NODES + 255) / 256, 256, 0, stream>>>(
            agg, ws_a + (size_t)(L - 1) * 1024, bs_a + (L - 1) * 32,
            ws_b + (size_t)L * 1024, bs_b + L * 32, ubuf, stats + L * 64);
    }
    // layer-5 BN + pooling
    k_bn_pool<<<(N_NODES * 32) / 256, 256, 0, stream>>>(ubuf, stats + 256, bn_g + 128, bn_b + 128, batch, pooled);

    // head
    k_gemm<<<dim3(32, 2), 256, 0, stream>>>(pooled, fcg_w, fcg_b, zcat, 128, 32, 256, 1);
    k_gemm<<<dim3(32, 4), 256, 0, stream>>>(sf, fs1_w, fs1_b, s1buf, 256, 512, 256, 1);
    k_gemm<<<dim3(32, 2), 256, 0, stream>>>(s1buf, fs2_w, fs2_b, zcat + 128, 128, 256, 256, 1);
    k_gemm<<<dim3(32, 16), 256, 0, stream>>>(zcat, fc1_w, fc1_b, z1buf, 1024, 256, 1024, 1);
    k_gemm<<<dim3(32, 4), 256, 0, stream>>>(z1buf, fc2_w, fc2_b, z2buf, 256, 1024, 256, 1);
    k_out<<<512, 256, 0, stream>>>(z2buf, out_w, out_b, dout);
}

// Round 3
// 778.606 us; speedup vs baseline: 3.6891x; 1.1264x over previous
//
#include <hip/hip_runtime.h>
#include <hip/hip_bf16.h>

static constexpr int N_NODES = 100000;
static constexpr int N_EDGES = 1600000;
static constexpr int N_GRAPH = 2048;
static constexpr float BN_EPS_C = 1e-5f;

typedef unsigned int uint;
typedef unsigned short ushort;

// ---------------- bf16 helpers (RNE pack, shift unpack) ----------------

__device__ inline uint pk2(float a, float b) {
    uint ua = __float_as_uint(a), ub = __float_as_uint(b);
    ua = (ua + 0x7fffu + ((ua >> 16) & 1u)) >> 16;
    ub = (ub + 0x7fffu + ((ub >> 16) & 1u)) >> 16;
    return ua | (ub << 16);
}
__device__ inline float b2f_lo(uint u) { return __uint_as_float(u << 16); }
__device__ inline float b2f_hi(uint u) { return __uint_as_float(u & 0xffff0000u); }

__device__ inline void unpack8(uint4 v, float* f) {
    f[0] = b2f_lo(v.x); f[1] = b2f_hi(v.x);
    f[2] = b2f_lo(v.y); f[3] = b2f_hi(v.y);
    f[4] = b2f_lo(v.z); f[5] = b2f_hi(v.z);
    f[6] = b2f_lo(v.w); f[7] = b2f_hi(v.w);
}

// ---------------- CSR build ----------------

__global__ __launch_bounds__(256) void k_hist(const int* __restrict__ dst, int* __restrict__ deg) {
    int i = blockIdx.x * 256 + threadIdx.x;
    if (i < N_EDGES) atomicAdd(&deg[__builtin_nontemporal_load(&dst[i])], 1);
}

__global__ __launch_bounds__(256) void k_scan_partial(const int* __restrict__ deg, int* __restrict__ part) {
    __shared__ int sw[4];
    int b = blockIdx.x, tid = threadIdx.x;
    int base = b * 1024;
    int s = 0;
#pragma unroll
    for (int r = 0; r < 4; ++r) {
        int i = base + r * 256 + tid;
        if (i < N_NODES) s += deg[i];
    }
#pragma unroll
    for (int off = 32; off > 0; off >>= 1) s += __shfl_down(s, off);
    if ((tid & 63) == 0) sw[tid >> 6] = s;
    __syncthreads();
    if (tid == 0) part[b] = sw[0] + sw[1] + sw[2] + sw[3];
}

__global__ __launch_bounds__(256) void k_scan_offsets(int* __restrict__ part, int nb) {
    __shared__ int sh[256];
    int tid = threadIdx.x;
    sh[tid] = (tid < nb) ? part[tid] : 0;
    __syncthreads();
    if (tid == 0) {
        int run = 0;
        for (int i = 0; i < nb; ++i) { int v = sh[i]; sh[i] = run; run += v; }
    }
    __syncthreads();
    if (tid < nb) part[tid] = sh[tid];
}

__global__ __launch_bounds__(256) void k_scan_final(const int* __restrict__ deg, const int* __restrict__ part,
                                                    int* __restrict__ row_ptr, int* __restrict__ cursor) {
    __shared__ int wsum[4];
    int b = blockIdx.x, tid = threadIdx.x;
    int lane = tid & 63, w = tid >> 6;
    int base = b * 1024 + tid * 4;
    int v[4];
#pragma unroll
    for (int r = 0; r < 4; ++r) {
        int i = base + r;
        v[r] = (i < N_NODES) ? deg[i] : 0;
    }
    int tsum = v[0] + v[1] + v[2] + v[3];
    int inc = tsum;
#pragma unroll
    for (int off = 1; off < 64; off <<= 1) {
        int t = __shfl_up(inc, off);
        if (lane >= off) inc += t;
    }
    if (lane == 63) wsum[w] = inc;
    __syncthreads();
    int woff = 0;
    for (int ww = 0; ww < w; ++ww) woff += wsum[ww];
    int run = part[b] + woff + (inc - tsum);
#pragma unroll
    for (int r = 0; r < 4; ++r) {
        int i = base + r;
        if (i < N_NODES) { row_ptr[i] = run; cursor[i] = run; }
        run += v[r];
    }
}

// Range-partitioned scatter: pass handles dst in [lo,hi) so the live ssrc
// window (~800KB) stays L2-resident and lines collect all ~16 entries before
// writeback (round-2: 105MB HBM writes for 6.4MB of data). NT loads keep the
// streaming edge reads from evicting the write window.
__global__ __launch_bounds__(256) void k_scatter_pass(const int* __restrict__ src, const int* __restrict__ dst,
                                                      int* __restrict__ cursor, int* __restrict__ ssrc,
                                                      int lo, int hi) {
    int i = blockIdx.x * 256 + threadIdx.x;
    if (i >= N_EDGES) return;
    int d = __builtin_nontemporal_load(&dst[i]);
    if (d >= lo && d < hi) {
        int s = __builtin_nontemporal_load(&src[i]);
        int p = atomicAdd(&cursor[d], 1);
        ssrc[p] = s;
    }
}

// ---------------- GIN aggregation ----------------

// Layer-1 over bf16 x (64 feats). 8 lanes/node, 8 bf16 (16B) each.
__global__ __launch_bounds__(256) void k_gather64b(const ushort* __restrict__ xb,
                                                   const int* __restrict__ row_ptr, const int* __restrict__ row_end,
                                                   const int* __restrict__ ssrc, float* __restrict__ out) {
    int idx = blockIdx.x * 256 + threadIdx.x;
    int node = idx >> 3;
    if (node >= N_NODES) return;
    int f8 = (idx & 7) * 8;
    float acc[8];
    unpack8(*(const uint4*)(xb + (size_t)node * 64 + f8), acc);
    int e1 = row_end[node];
    for (int e = row_ptr[node]; e < e1; ++e) {
        int s = ssrc[e];
        float v[8];
        unpack8(*(const uint4*)(xb + (size_t)s * 64 + f8), v);
#pragma unroll
        for (int j = 0; j < 8; ++j) acc[j] += v[j];
    }
    float* op = out + (size_t)node * 64 + f8;
    *(float4*)op = make_float4(acc[0], acc[1], acc[2], acc[3]);
    *(float4*)(op + 4) = make_float4(acc[4], acc[5], acc[6], acc[7]);
}

// fp32 fallback (used when ws_size can't hold the bf16 copy of x)
__global__ __launch_bounds__(256) void k_gather64(const float* __restrict__ x,
                                                  const int* __restrict__ row_ptr, const int* __restrict__ row_end,
                                                  const int* __restrict__ ssrc, float* __restrict__ out) {
    int idx = blockIdx.x * 256 + threadIdx.x;
    int node = idx >> 4;
    if (node >= N_NODES) return;
    int f = (idx & 15) * 4;
    float4 acc = *(const float4*)(x + (size_t)node * 64 + f);
    int e1 = row_end[node];
    for (int e = row_ptr[node]; e < e1; ++e) {
        int s = ssrc[e];
        float4 v = *(const float4*)(x + (size_t)s * 64 + f);
        acc.x += v.x; acc.y += v.y; acc.z += v.z; acc.w += v.w;
    }
    *(float4*)(out + (size_t)node * 64 + f) = acc;
}

// Layers 2-5: gather bf16 u rows (64B = one cache line per edge) with the
// previous layer's BN+ReLU fused. 4 lanes/node, 8 bf16 each.
__global__ __launch_bounds__(256) void k_gather_bn_b(const ushort* __restrict__ u, const float* __restrict__ stats,
                                                     const float* __restrict__ bng, const float* __restrict__ bnb,
                                                     const int* __restrict__ row_ptr, const int* __restrict__ row_end,
                                                     const int* __restrict__ ssrc, float* __restrict__ out) {
    int idx = blockIdx.x * 256 + threadIdx.x;
    int node = idx >> 2;
    if (node >= N_NODES) return;
    int f8 = (idx & 3) * 8;
    const float inv = 1.0f / (float)N_NODES;
    float sc[8], sh[8];
    {
        float s1[8], s2[8], g[8], b[8];
        *(float4*)s1 = *(const float4*)(stats + f8);       *(float4*)(s1 + 4) = *(const float4*)(stats + f8 + 4);
        *(float4*)s2 = *(const float4*)(stats + 32 + f8);  *(float4*)(s2 + 4) = *(const float4*)(stats + 36 + f8);
        *(float4*)g  = *(const float4*)(bng + f8);         *(float4*)(g + 4)  = *(const float4*)(bng + f8 + 4);
        *(float4*)b  = *(const float4*)(bnb + f8);         *(float4*)(b + 4)  = *(const float4*)(bnb + f8 + 4);
#pragma unroll
        for (int j = 0; j < 8; ++j) {
            float mu = s1[j] * inv;
            sc[j] = rsqrtf(s2[j] * inv - mu * mu + BN_EPS_C) * g[j];
            sh[j] = b[j] - mu * sc[j];
        }
    }
    float acc[8], v[8];
    unpack8(*(const uint4*)(u + (size_t)node * 32 + f8), v);
#pragma unroll
    for (int j = 0; j < 8; ++j) acc[j] = fmaxf(fmaf(v[j], sc[j], sh[j]), 0.f);
    int e1 = row_end[node];
    for (int e = row_ptr[node]; e < e1; ++e) {
        int s = ssrc[e];
        unpack8(*(const uint4*)(u + (size_t)s * 32 + f8), v);
#pragma unroll
        for (int j = 0; j < 8; ++j) acc[j] += fmaxf(fmaf(v[j], sc[j], sh[j]), 0.f);
    }
    float* op = out + (size_t)node * 32 + f8;
    *(float4*)op = make_float4(acc[0], acc[1], acc[2], acc[3]);
    *(float4*)(op + 4) = make_float4(acc[4], acc[5], acc[6], acc[7]);
}

// ---------------- node MLP + BN-stats (phase-split via LDS; u out = bf16) ----------------

template <int K>
__global__ __launch_bounds__(256) void k_mlp_stats(const float* __restrict__ agg,
                                                   const float* __restrict__ Wa, const float* __restrict__ ba,
                                                   const float* __restrict__ Wb, const float* __restrict__ bb,
                                                   ushort* __restrict__ u, float* __restrict__ stats) {
    __shared__ float sWa[K * 32];
    __shared__ float sWb[1024];
    __shared__ float sba[32];
    __shared__ float sbb[32];
    __shared__ float tile[256][33];
    __shared__ float bstats[64];
    int tid = threadIdx.x;
    for (int i = tid; i < K * 32; i += 256) sWa[i] = Wa[i];
    for (int i = tid; i < 1024; i += 256) sWb[i] = Wb[i];
    if (tid < 32) { sba[tid] = ba[tid]; sbb[tid] = bb[tid]; }
    if (tid < 64) bstats[tid] = 0.f;
    __syncthreads();
    int node = blockIdx.x * 256 + tid;
    bool active = node < N_NODES;

    {
        float t[32];
#pragma unroll
        for (int j = 0; j < 32; ++j) t[j] = sba[j];
        if (active) {
            const float* arow = agg + (size_t)node * K;
            for (int k = 0; k < K; k += 4) {
                float4 a4 = *(const float4*)(arow + k);
                float av[4] = {a4.x, a4.y, a4.z, a4.w};
#pragma unroll
                for (int kk = 0; kk < 4; ++kk) {
                    float a = av[kk];
                    const float4* wr = (const float4*)(sWa + (k + kk) * 32);
#pragma unroll
                    for (int j4 = 0; j4 < 8; ++j4) {
                        float4 wv = wr[j4];
                        t[j4 * 4 + 0] = fmaf(a, wv.x, t[j4 * 4 + 0]);
                        t[j4 * 4 + 1] = fmaf(a, wv.y, t[j4 * 4 + 1]);
                        t[j4 * 4 + 2] = fmaf(a, wv.z, t[j4 * 4 + 2]);
                        t[j4 * 4 + 3] = fmaf(a, wv.w, t[j4 * 4 + 3]);
                    }
                }
            }
        }
#pragma unroll
        for (int j = 0; j < 32; ++j) tile[tid][j] = fmaxf(t[j], 0.f);
    }
    __syncthreads();

    float uu[32];
#pragma unroll
    for (int j = 0; j < 32; ++j) uu[j] = sbb[j];
#pragma unroll 4
    for (int k = 0; k < 32; ++k) {
        float a = tile[tid][k];
        const float4* wr = (const float4*)(sWb + k * 32);
#pragma unroll
        for (int j4 = 0; j4 < 8; ++j4) {
            float4 wv = wr[j4];
            uu[j4 * 4 + 0] = fmaf(a, wv.x, uu[j4 * 4 + 0]);
            uu[j4 * 4 + 1] = fmaf(a, wv.y, uu[j4 * 4 + 1]);
            uu[j4 * 4 + 2] = fmaf(a, wv.z, uu[j4 * 4 + 2]);
            uu[j4 * 4 + 3] = fmaf(a, wv.w, uu[j4 * 4 + 3]);
        }
    }
    if (active) {
        uint pk[16];
#pragma unroll
        for (int j = 0; j < 16; ++j) pk[j] = pk2(uu[2 * j], uu[2 * j + 1]);
        uint4* up = (uint4*)(u + (size_t)node * 32);
        up[0] = make_uint4(pk[0], pk[1], pk[2], pk[3]);
        up[1] = make_uint4(pk[4], pk[5], pk[6], pk[7]);
        up[2] = make_uint4(pk[8], pk[9], pk[10], pk[11]);
        up[3] = make_uint4(pk[12], pk[13], pk[14], pk[15]);
    } else {
#pragma unroll
        for (int j = 0; j < 32; ++j) uu[j] = 0.f;
    }

#pragma unroll
    for (int j = 0; j < 32; ++j) {
        float v = uu[j];
        float v2 = v * v;
#pragma unroll
        for (int off = 32; off > 0; off >>= 1) {
            v += __shfl_down(v, off);
            v2 += __shfl_down(v2, off);
        }
        if ((tid & 63) == 0) {
            atomicAdd(&bstats[j], v);
            atomicAdd(&bstats[32 + j], v2);
        }
    }
    __syncthreads();
    if (tid < 64) atomicAdd(&stats[tid], bstats[tid]);
}

// ---------------- layer-5 BN + graph pooling (batch is sorted: segmented) ----------------

__global__ __launch_bounds__(256) void k_bn_pool(const ushort* __restrict__ u, const float* __restrict__ stats,
                                                 const float* __restrict__ bng, const float* __restrict__ bnb,
                                                 const int* __restrict__ batch, float* __restrict__ pooled) {
    const int CH = 128;
    int wid = (blockIdx.x * 256 + threadIdx.x) >> 6;
    int lane = threadIdx.x & 63;
    int f = lane & 31, par = lane >> 5;
    int n0 = wid * CH;
    if (n0 >= N_NODES) return;
    int n1 = n0 + CH; if (n1 > N_NODES) n1 = N_NODES;
    const float inv = 1.0f / (float)N_NODES;
    float mu = stats[f] * inv;
    float var = stats[32 + f] * inv - mu * mu;
    float sc = rsqrtf(var + BN_EPS_C) * bng[f];
    float sh = bnb[f] - mu * sc;
    float acc = 0.f;
    int curg = -1;
    for (int n = n0 + par; n < n1; n += 2) {
        int g = batch[n];
        if (g != curg) {
            if (curg >= 0) atomicAdd(&pooled[(size_t)curg * 32 + f], acc);
            acc = 0.f; curg = g;
        }
        float v = b2f_lo((uint)u[(size_t)n * 32 + f]);
        acc += fmaxf(fmaf(v, sc, sh), 0.f);
    }
    if (curg >= 0) atomicAdd(&pooled[(size_t)curg * 32 + f], acc);
}

// ---------------- x -> bf16 conversion ----------------

__global__ __launch_bounds__(256) void k_cvt_bf16(const float* __restrict__ x, ushort* __restrict__ xb, int n) {
    int i = (blockIdx.x * 256 + threadIdx.x) * 8;
    if (i >= n) return;
    float4 a = *(const float4*)(x + i);
    float4 b = *(const float4*)(x + i + 4);
    *(uint4*)(xb + i) = make_uint4(pk2(a.x, a.y), pk2(a.z, a.w), pk2(b.x, b.y), pk2(b.z, b.w));
}

// ---------------- generic head GEMM ----------------

__global__ __launch_bounds__(256) void k_gemm(const float* __restrict__ A, const float* __restrict__ B,
                                              const float* __restrict__ bias, float* __restrict__ C,
                                              int Nc, int K, int ldc, int do_relu) {
    __shared__ float As[16][64];
    __shared__ float Bs[16][64];
    int tid = threadIdx.x;
    int tx = tid & 15, ty = tid >> 4;
    int bm = blockIdx.x * 64, bn = blockIdx.y * 64;
    float acc[4][4] = {{0.f}};
    int am = tid >> 2;
    int ak = (tid & 3) * 4;
    int bk = tid >> 4;
    int bn4 = (tid & 15) * 4;
    const float* Ap = A + (size_t)(bm + am) * K + ak;
    const float* Bp = B + (size_t)bk * Nc + bn + bn4;
    for (int k0 = 0; k0 < K; k0 += 16) {
        float4 av = *(const float4*)(Ap + k0);
        float4 bv = *(const float4*)(Bp + (size_t)k0 * Nc);
        As[ak + 0][am] = av.x;
        As[ak + 1][am] = av.y;
        As[ak + 2][am] = av.z;
        As[ak + 3][am] = av.w;
        *(float4*)&Bs[bk][bn4] = bv;
        __syncthreads();
#pragma unroll
        for (int k = 0; k < 16; ++k) {
            float4 a4 = *(const float4*)&As[k][ty * 4];
            float4 b4 = *(const float4*)&Bs[k][tx * 4];
            acc[0][0] = fmaf(a4.x, b4.x, acc[0][0]);
            acc[0][1] = fmaf(a4.x, b4.y, acc[0][1]);
            acc[0][2] = fmaf(a4.x, b4.z, acc[0][2]);
            acc[0][3] = fmaf(a4.x, b4.w, acc[0][3]);
            acc[1][0] = fmaf(a4.y, b4.x, acc[1][0]);
            acc[1][1] = fmaf(a4.y, b4.y, acc[1][1]);
            acc[1][2] = fmaf(a4.y, b4.z, acc[1][2]);
            acc[1][3] = fmaf(a4.y, b4.w, acc[1][3]);
            acc[2][0] = fmaf(a4.z, b4.x, acc[2][0]);
            acc[2][1] = fmaf(a4.z, b4.y, acc[2][1]);
            acc[2][2] = fmaf(a4.z, b4.z, acc[2][2]);
            acc[2][3] = fmaf(a4.z, b4.w, acc[2][3]);
            acc[3][0] = fmaf(a4.w, b4.x, acc[3][0]);
            acc[3][1] = fmaf(a4.w, b4.y, acc[3][1]);
            acc[3][2] = fmaf(a4.w, b4.z, acc[3][2]);
            acc[3][3] = fmaf(a4.w, b4.w, acc[3][3]);
        }
        __syncthreads();
    }
    float4 bi = *(const float4*)(bias + bn + tx * 4);
#pragma unroll
    for (int i = 0; i < 4; ++i) {
        float4 v;
        v.x = acc[i][0] + bi.x;
        v.y = acc[i][1] + bi.y;
        v.z = acc[i][2] + bi.z;
        v.w = acc[i][3] + bi.w;
        if (do_relu) {
            v.x = fmaxf(v.x, 0.f); v.y = fmaxf(v.y, 0.f);
            v.z = fmaxf(v.z, 0.f); v.w = fmaxf(v.w, 0.f);
        }
        *(float4*)(C + (size_t)(bm + ty * 4 + i) * ldc + bn + tx * 4) = v;
    }
}

// ---------------- final dot ----------------

__global__ __launch_bounds__(256) void k_out(const float* __restrict__ z2, const float* __restrict__ w,
                                             const float* __restrict__ b, float* __restrict__ out) {
    int gid = blockIdx.x * 256 + threadIdx.x;
    int g = gid >> 6;
    int lane = threadIdx.x & 63;
    if (g >= N_GRAPH) return;
    float4 a = *(const float4*)(z2 + (size_t)g * 256 + lane * 4);
    float4 wv = *(const float4*)(w + lane * 4);
    float v = a.x * wv.x + a.y * wv.y + a.z * wv.z + a.w * wv.w;
#pragma unroll
    for (int off = 32; off > 0; off >>= 1) v += __shfl_down(v, off);
    if (lane == 0) out[g] = v + b[0];
}

// ---------------- launcher ----------------

extern "C" void kernel_launch(void* const* d_in, const int* in_sizes, int n_in,
                              void* d_out, int out_size, void* d_ws, size_t ws_size,
                              hipStream_t stream) {
    const float* x     = (const float*)d_in[0];
    const int*   eidx  = (const int*)d_in[1];
    const int*   batch = (const int*)d_in[2];
    const float* sf    = (const float*)d_in[3];
    const float* w1a   = (const float*)d_in[4];
    const float* b1a   = (const float*)d_in[5];
    const float* ws_a  = (const float*)d_in[6];
    const float* bs_a  = (const float*)d_in[7];
    const float* ws_b  = (const float*)d_in[8];
    const float* bs_b  = (const float*)d_in[9];
    const float* bn_g  = (const float*)d_in[10];
    const float* bn_b  = (const float*)d_in[11];
    const float* fcg_w = (const float*)d_in[12];
    const float* fcg_b = (const float*)d_in[13];
    const float* fs1_w = (const float*)d_in[14];
    const float* fs1_b = (const float*)d_in[15];
    const float* fs2_w = (const float*)d_in[16];
    const float* fs2_b = (const float*)d_in[17];
    const float* fc1_w = (const float*)d_in[18];
    const float* fc1_b = (const float*)d_in[19];
    const float* fc2_w = (const float*)d_in[20];
    const float* fc2_b = (const float*)d_in[21];
    const float* out_w = (const float*)d_in[22];
    const float* out_b = (const float*)d_in[23];
    float* dout = (float*)d_out;

    char* p = (char*)d_ws;
    float*  agg     = (float*)p;  p += (size_t)N_NODES * 64 * 4;   // 25.6 MB
    ushort* ubuf    = (ushort*)p; p += (size_t)N_NODES * 32 * 2;   // 6.4 MB
    int*    ssrc    = (int*)p;    p += (size_t)N_EDGES * 4;        // 6.4 MB
    int*    row_ptr = (int*)p;    p += (size_t)N_NODES * 4;
    int*    cursor  = (int*)p;    p += (size_t)N_NODES * 4;
    int*    part    = (int*)p;    p += 512 * 4;
    int*    deg     = (int*)p;    p += (size_t)N_NODES * 4;        // zero start
    float*  stats   = (float*)p;  p += 320 * 4;
    float*  pooled  = (float*)p;  p += (size_t)N_GRAPH * 32 * 4;   // zero end
    ushort* xb      = (ushort*)p; p += (size_t)N_NODES * 64 * 2;   // 12.8 MB (optional)
    bool use_xb = ((size_t)(p - (char*)d_ws) <= ws_size);

    // head buffers alias agg (dead by head time)
    float* s1buf = agg;                  // 2048*256
    float* zcat  = agg + 2048 * 256;     // 2048*256
    float* z1buf = zcat + 2048 * 256;    // 2048*1024
    float* z2buf = z1buf + 2048 * 1024;  // 2048*256

    size_t zero_bytes = ((size_t)N_NODES + 320 + (size_t)N_GRAPH * 32) * 4;
    hipMemsetAsync(deg, 0, zero_bytes, stream);

    const int* esrc = eidx;
    const int* edst = eidx + N_EDGES;
    int nb = (N_NODES + 1023) / 1024;  // 98

    k_hist<<<N_EDGES / 256, 256, 0, stream>>>(edst, deg);
    k_scan_partial<<<nb, 256, 0, stream>>>(deg, part);
    k_scan_offsets<<<1, 256, 0, stream>>>(part, nb);
    k_scan_final<<<nb, 256, 0, stream>>>(deg, part, row_ptr, cursor);
    for (int k = 0; k < 8; ++k) {
        int lo = k * 12500;
        int hi = (k == 7) ? N_NODES : lo + 12500;
        k_scatter_pass<<<N_EDGES / 256, 256, 0, stream>>>(esrc, edst, cursor, ssrc, lo, hi);
    }

    // layer 1
    if (use_xb) {
        k_cvt_bf16<<<(N_NODES * 64 / 8 + 255) / 256, 256, 0, stream>>>(x, xb, N_NODES * 64);
        k_gather64b<<<(N_NODES * 8) / 256, 256, 0, stream>>>(xb, row_ptr, cursor, ssrc, agg);
    } else {
        k_gather64<<<(N_NODES * 16) / 256, 256, 0, stream>>>(x, row_ptr, cursor, ssrc, agg);
    }
    k_mlp_stats<64><<<(N_NODES + 255) / 256, 256, 0, stream>>>(agg, w1a, b1a, ws_b, bs_b, ubuf, stats);
    // layers 2-5
    for (int L = 1; L <= 4; ++L) {
        k_gather_bn_b<<<(N_NODES * 4 + 255) / 256, 256, 0, stream>>>(
            ubuf, stats + (L - 1) * 64, bn_g + (L - 1) * 32, bn_b + (L - 1) * 32,
            row_ptr, cursor, ssrc, agg);
        k_mlp_stats<32><<<(N_NODES + 255) / 256, 256, 0, stream>>>(
            agg, ws_a + (size_t)(L - 1) * 1024, bs_a + (L - 1) * 32,
            ws_b + (size_t)L * 1024, bs_b + L * 32, ubuf, stats + L * 64);
    }
    // layer-5 BN + pooling (segmented over sorted batch)
    {
        int waves = (N_NODES + 127) / 128;
        int blocks = (waves + 3) / 4;
        k_bn_pool<<<blocks, 256, 0, stream>>>(ubuf, stats + 256, bn_g + 128, bn_b + 128, batch, pooled);
    }

    // head
    k_gemm<<<dim3(32, 2), 256, 0, stream>>>(pooled, fcg_w, fcg_b, zcat, 128, 32, 256, 1);
    k_gemm<<<dim3(32, 4), 256, 0, stream>>>(sf, fs1_w, fs1_b, s1buf, 256, 512, 256, 1);
    k_gemm<<<dim3(32, 2), 256, 0, stream>>>(s1buf, fs2_w, fs2_b, zcat + 128, 128, 256, 256, 1);
    k_gemm<<<dim3(32, 16), 256, 0, stream>>>(zcat, fc1_w, fc1_b, z1buf, 1024, 256, 1024, 1);
    k_gemm<<<dim3(32, 4), 256, 0, stream>>>(z1buf, fc2_w, fc2_b, z2buf, 256, 1024, 256, 1);
    k_out<<<512, 256, 0, stream>>>(z2buf, out_w, out_b, dout);
}

// Round 4
// 686.990 us; speedup vs baseline: 4.1811x; 1.1334x over previous
//
#include <hip/hip_runtime.h>
#include <hip/hip_bf16.h>

static constexpr int N_NODES = 100000;
static constexpr int N_EDGES = 1600000;
static constexpr int N_GRAPH = 2048;
static constexpr float BN_EPS_C = 1e-5f;

typedef unsigned int uint;
typedef unsigned short ushort;

// ---------------- bf16 helpers (RNE pack, shift unpack) ----------------

__device__ inline uint pk2(float a, float b) {
    uint ua = __float_as_uint(a), ub = __float_as_uint(b);
    ua = (ua + 0x7fffu + ((ua >> 16) & 1u)) >> 16;
    ub = (ub + 0x7fffu + ((ub >> 16) & 1u)) >> 16;
    return ua | (ub << 16);
}
__device__ inline float b2f_lo(uint u) { return __uint_as_float(u << 16); }
__device__ inline float b2f_hi(uint u) { return __uint_as_float(u & 0xffff0000u); }

__device__ inline void unpack8(uint4 v, float* f) {
    f[0] = b2f_lo(v.x); f[1] = b2f_hi(v.x);
    f[2] = b2f_lo(v.y); f[3] = b2f_hi(v.y);
    f[4] = b2f_lo(v.z); f[5] = b2f_hi(v.z);
    f[6] = b2f_lo(v.w); f[7] = b2f_hi(v.w);
}

// ---------------- CSR build ----------------

__global__ __launch_bounds__(256) void k_hist(const int* __restrict__ dst, int* __restrict__ deg) {
    int i = blockIdx.x * 256 + threadIdx.x;
    if (i < N_EDGES) atomicAdd(&deg[__builtin_nontemporal_load(&dst[i])], 1);
}

__global__ __launch_bounds__(256) void k_scan_partial(const int* __restrict__ deg, int* __restrict__ part) {
    __shared__ int sw[4];
    int b = blockIdx.x, tid = threadIdx.x;
    int base = b * 1024;
    int s = 0;
#pragma unroll
    for (int r = 0; r < 4; ++r) {
        int i = base + r * 256 + tid;
        if (i < N_NODES) s += deg[i];
    }
#pragma unroll
    for (int off = 32; off > 0; off >>= 1) s += __shfl_down(s, off);
    if ((tid & 63) == 0) sw[tid >> 6] = s;
    __syncthreads();
    if (tid == 0) part[b] = sw[0] + sw[1] + sw[2] + sw[3];
}

__global__ __launch_bounds__(256) void k_scan_offsets(int* __restrict__ part, int nb) {
    __shared__ int sh[256];
    int tid = threadIdx.x;
    sh[tid] = (tid < nb) ? part[tid] : 0;
    __syncthreads();
    if (tid == 0) {
        int run = 0;
        for (int i = 0; i < nb; ++i) { int v = sh[i]; sh[i] = run; run += v; }
    }
    __syncthreads();
    if (tid < nb) part[tid] = sh[tid];
}

__global__ __launch_bounds__(256) void k_scan_final(const int* __restrict__ deg, const int* __restrict__ part,
                                                    int* __restrict__ row_ptr, int* __restrict__ cursor) {
    __shared__ int wsum[4];
    int b = blockIdx.x, tid = threadIdx.x;
    int lane = tid & 63, w = tid >> 6;
    int base = b * 1024 + tid * 4;
    int v[4];
#pragma unroll
    for (int r = 0; r < 4; ++r) {
        int i = base + r;
        v[r] = (i < N_NODES) ? deg[i] : 0;
    }
    int tsum = v[0] + v[1] + v[2] + v[3];
    int inc = tsum;
#pragma unroll
    for (int off = 1; off < 64; off <<= 1) {
        int t = __shfl_up(inc, off);
        if (lane >= off) inc += t;
    }
    if (lane == 63) wsum[w] = inc;
    __syncthreads();
    int woff = 0;
    for (int ww = 0; ww < w; ++ww) woff += wsum[ww];
    int run = part[b] + woff + (inc - tsum);
#pragma unroll
    for (int r = 0; r < 4; ++r) {
        int i = base + r;
        if (i < N_NODES) { row_ptr[i] = run; cursor[i] = run; }
        run += v[r];
    }
}

// Range-partitioned scatter (R2 fix: 105MB HBM writes -> L2-resident window).
__global__ __launch_bounds__(256) void k_scatter_pass(const int* __restrict__ src, const int* __restrict__ dst,
                                                      int* __restrict__ cursor, int* __restrict__ ssrc,
                                                      int lo, int hi) {
    int i = blockIdx.x * 256 + threadIdx.x;
    if (i >= N_EDGES) return;
    int d = __builtin_nontemporal_load(&dst[i]);
    if (d >= lo && d < hi) {
        int s = __builtin_nontemporal_load(&src[i]);
        int p = atomicAdd(&cursor[d], 1);
        ssrc[p] = s;
    }
}

// ---------------- GIN aggregation ----------------

// Layer-1 over bf16 x (64 feats). 8 lanes/node; unroll-2 edge pipeline.
__global__ __launch_bounds__(256) void k_gather64b(const ushort* __restrict__ xb,
                                                   const int* __restrict__ row_ptr, const int* __restrict__ row_end,
                                                   const int* __restrict__ ssrc, float* __restrict__ out) {
    int idx = blockIdx.x * 256 + threadIdx.x;
    int node = idx >> 3;
    if (node >= N_NODES) return;
    int f8 = (idx & 7) * 8;
    float acc[8];
    unpack8(*(const uint4*)(xb + (size_t)node * 64 + f8), acc);
    int e = row_ptr[node], e1 = row_end[node];
    for (; e + 2 <= e1; e += 2) {
        int s0 = ssrc[e], s1 = ssrc[e + 1];
        uint4 va = *(const uint4*)(xb + (size_t)s0 * 64 + f8);
        uint4 vb = *(const uint4*)(xb + (size_t)s1 * 64 + f8);
        float v[8];
        unpack8(va, v);
#pragma unroll
        for (int j = 0; j < 8; ++j) acc[j] += v[j];
        unpack8(vb, v);
#pragma unroll
        for (int j = 0; j < 8; ++j) acc[j] += v[j];
    }
    if (e < e1) {
        int s = ssrc[e];
        float v[8];
        unpack8(*(const uint4*)(xb + (size_t)s * 64 + f8), v);
#pragma unroll
        for (int j = 0; j < 8; ++j) acc[j] += v[j];
    }
    float* op = out + (size_t)node * 64 + f8;
    *(float4*)op = make_float4(acc[0], acc[1], acc[2], acc[3]);
    *(float4*)(op + 4) = make_float4(acc[4], acc[5], acc[6], acc[7]);
}

// fp32 fallback
__global__ __launch_bounds__(256) void k_gather64(const float* __restrict__ x,
                                                  const int* __restrict__ row_ptr, const int* __restrict__ row_end,
                                                  const int* __restrict__ ssrc, float* __restrict__ out) {
    int idx = blockIdx.x * 256 + threadIdx.x;
    int node = idx >> 4;
    if (node >= N_NODES) return;
    int f = (idx & 15) * 4;
    float4 acc = *(const float4*)(x + (size_t)node * 64 + f);
    int e1 = row_end[node];
    for (int e = row_ptr[node]; e < e1; ++e) {
        int s = ssrc[e];
        float4 v = *(const float4*)(x + (size_t)s * 64 + f);
        acc.x += v.x; acc.y += v.y; acc.z += v.z; acc.w += v.w;
    }
    *(float4*)(out + (size_t)node * 64 + f) = acc;
}

// Layers 2-5: bf16 u rows (64B = one line/edge), prev BN+ReLU fused; unroll-2.
__global__ __launch_bounds__(256) void k_gather_bn_b(const ushort* __restrict__ u, const float* __restrict__ stats,
                                                     const float* __restrict__ bng, const float* __restrict__ bnb,
                                                     const int* __restrict__ row_ptr, const int* __restrict__ row_end,
                                                     const int* __restrict__ ssrc, float* __restrict__ out) {
    int idx = blockIdx.x * 256 + threadIdx.x;
    int node = idx >> 2;
    if (node >= N_NODES) return;
    int f8 = (idx & 3) * 8;
    const float inv = 1.0f / (float)N_NODES;
    float sc[8], sh[8];
    {
        float s1[8], s2[8], g[8], b[8];
        *(float4*)s1 = *(const float4*)(stats + f8);       *(float4*)(s1 + 4) = *(const float4*)(stats + f8 + 4);
        *(float4*)s2 = *(const float4*)(stats + 32 + f8);  *(float4*)(s2 + 4) = *(const float4*)(stats + 36 + f8);
        *(float4*)g  = *(const float4*)(bng + f8);         *(float4*)(g + 4)  = *(const float4*)(bng + f8 + 4);
        *(float4*)b  = *(const float4*)(bnb + f8);         *(float4*)(b + 4)  = *(const float4*)(bnb + f8 + 4);
#pragma unroll
        for (int j = 0; j < 8; ++j) {
            float mu = s1[j] * inv;
            sc[j] = rsqrtf(s2[j] * inv - mu * mu + BN_EPS_C) * g[j];
            sh[j] = b[j] - mu * sc[j];
        }
    }
    float acc[8], v[8];
    unpack8(*(const uint4*)(u + (size_t)node * 32 + f8), v);
#pragma unroll
    for (int j = 0; j < 8; ++j) acc[j] = fmaxf(fmaf(v[j], sc[j], sh[j]), 0.f);
    int e = row_ptr[node], e1 = row_end[node];
    for (; e + 2 <= e1; e += 2) {
        int s0 = ssrc[e], s1 = ssrc[e + 1];
        uint4 va = *(const uint4*)(u + (size_t)s0 * 32 + f8);
        uint4 vb = *(const uint4*)(u + (size_t)s1 * 32 + f8);
        unpack8(va, v);
#pragma unroll
        for (int j = 0; j < 8; ++j) acc[j] += fmaxf(fmaf(v[j], sc[j], sh[j]), 0.f);
        unpack8(vb, v);
#pragma unroll
        for (int j = 0; j < 8; ++j) acc[j] += fmaxf(fmaf(v[j], sc[j], sh[j]), 0.f);
    }
    if (e < e1) {
        int s = ssrc[e];
        unpack8(*(const uint4*)(u + (size_t)s * 32 + f8), v);
#pragma unroll
        for (int j = 0; j < 8; ++j) acc[j] += fmaxf(fmaf(v[j], sc[j], sh[j]), 0.f);
    }
    float* op = out + (size_t)node * 32 + f8;
    *(float4*)op = make_float4(acc[0], acc[1], acc[2], acc[3]);
    *(float4*)(op + 4) = make_float4(acc[4], acc[5], acc[6], acc[7]);
}

// ---------------- node MLP + BN-stats (phase-split via LDS; u out = bf16) ----------------

template <int K>
__global__ __launch_bounds__(256) void k_mlp_stats(const float* __restrict__ agg,
                                                   const float* __restrict__ Wa, const float* __restrict__ ba,
                                                   const float* __restrict__ Wb, const float* __restrict__ bb,
                                                   ushort* __restrict__ u, float* __restrict__ stats) {
    __shared__ float sWa[K * 32];
    __shared__ float sWb[1024];
    __shared__ float sba[32];
    __shared__ float sbb[32];
    __shared__ float tile[256][33];
    __shared__ float bstats[64];
    int tid = threadIdx.x;
    for (int i = tid; i < K * 32; i += 256) sWa[i] = Wa[i];
    for (int i = tid; i < 1024; i += 256) sWb[i] = Wb[i];
    if (tid < 32) { sba[tid] = ba[tid]; sbb[tid] = bb[tid]; }
    if (tid < 64) bstats[tid] = 0.f;
    __syncthreads();
    int node = blockIdx.x * 256 + tid;
    bool active = node < N_NODES;

    {
        float t[32];
#pragma unroll
        for (int j = 0; j < 32; ++j) t[j] = sba[j];
        if (active) {
            const float* arow = agg + (size_t)node * K;
            for (int k = 0; k < K; k += 4) {
                float4 a4 = *(const float4*)(arow + k);
                float av[4] = {a4.x, a4.y, a4.z, a4.w};
#pragma unroll
                for (int kk = 0; kk < 4; ++kk) {
                    float a = av[kk];
                    const float4* wr = (const float4*)(sWa + (k + kk) * 32);
#pragma unroll
                    for (int j4 = 0; j4 < 8; ++j4) {
                        float4 wv = wr[j4];
                        t[j4 * 4 + 0] = fmaf(a, wv.x, t[j4 * 4 + 0]);
                        t[j4 * 4 + 1] = fmaf(a, wv.y, t[j4 * 4 + 1]);
                        t[j4 * 4 + 2] = fmaf(a, wv.z, t[j4 * 4 + 2]);
                        t[j4 * 4 + 3] = fmaf(a, wv.w, t[j4 * 4 + 3]);
                    }
                }
            }
        }
#pragma unroll
        for (int j = 0; j < 32; ++j) tile[tid][j] = fmaxf(t[j], 0.f);
    }
    __syncthreads();

    float uu[32];
#pragma unroll
    for (int j = 0; j < 32; ++j) uu[j] = sbb[j];
#pragma unroll 4
    for (int k = 0; k < 32; ++k) {
        float a = tile[tid][k];
        const float4* wr = (const float4*)(sWb + k * 32);
#pragma unroll
        for (int j4 = 0; j4 < 8; ++j4) {
            float4 wv = wr[j4];
            uu[j4 * 4 + 0] = fmaf(a, wv.x, uu[j4 * 4 + 0]);
            uu[j4 * 4 + 1] = fmaf(a, wv.y, uu[j4 * 4 + 1]);
            uu[j4 * 4 + 2] = fmaf(a, wv.z, uu[j4 * 4 + 2]);
            uu[j4 * 4 + 3] = fmaf(a, wv.w, uu[j4 * 4 + 3]);
        }
    }
    if (active) {
        uint pk[16];
#pragma unroll
        for (int j = 0; j < 16; ++j) pk[j] = pk2(uu[2 * j], uu[2 * j + 1]);
        uint4* up = (uint4*)(u + (size_t)node * 32);
        up[0] = make_uint4(pk[0], pk[1], pk[2], pk[3]);
        up[1] = make_uint4(pk[4], pk[5], pk[6], pk[7]);
        up[2] = make_uint4(pk[8], pk[9], pk[10], pk[11]);
        up[3] = make_uint4(pk[12], pk[13], pk[14], pk[15]);
    } else {
#pragma unroll
        for (int j = 0; j < 32; ++j) uu[j] = 0.f;
    }

#pragma unroll
    for (int j = 0; j < 32; ++j) {
        float v = uu[j];
        float v2 = v * v;
#pragma unroll
        for (int off = 32; off > 0; off >>= 1) {
            v += __shfl_down(v, off);
            v2 += __shfl_down(v2, off);
        }
        if ((tid & 63) == 0) {
            atomicAdd(&bstats[j], v);
            atomicAdd(&bstats[32 + j], v2);
        }
    }
    __syncthreads();
    if (tid < 64) atomicAdd(&stats[tid], bstats[tid]);
}

// ---------------- layer-5 BN + graph pooling (segmented over sorted batch) ----------------

__global__ __launch_bounds__(256) void k_bn_pool(const ushort* __restrict__ u, const float* __restrict__ stats,
                                                 const float* __restrict__ bng, const float* __restrict__ bnb,
                                                 const int* __restrict__ batch, float* __restrict__ pooled) {
    const int CH = 128;
    int wid = (blockIdx.x * 256 + threadIdx.x) >> 6;
    int lane = threadIdx.x & 63;
    int f = lane & 31, par = lane >> 5;
    int n0 = wid * CH;
    if (n0 >= N_NODES) return;
    int n1 = n0 + CH; if (n1 > N_NODES) n1 = N_NODES;
    const float inv = 1.0f / (float)N_NODES;
    float mu = stats[f] * inv;
    float var = stats[32 + f] * inv - mu * mu;
    float sc = rsqrtf(var + BN_EPS_C) * bng[f];
    float sh = bnb[f] - mu * sc;
    float acc = 0.f;
    int curg = -1;
    for (int n = n0 + par; n < n1; n += 2) {
        int g = batch[n];
        if (g != curg) {
            if (curg >= 0) atomicAdd(&pooled[(size_t)curg * 32 + f], acc);
            acc = 0.f; curg = g;
        }
        float v = b2f_lo((uint)u[(size_t)n * 32 + f]);
        acc += fmaxf(fmaf(v, sc, sh), 0.f);
    }
    if (curg >= 0) atomicAdd(&pooled[(size_t)curg * 32 + f], acc);
}

// ---------------- x -> bf16 conversion ----------------

__global__ __launch_bounds__(256) void k_cvt_bf16(const float* __restrict__ x, ushort* __restrict__ xb, int n) {
    int i = (blockIdx.x * 256 + threadIdx.x) * 8;
    if (i >= n) return;
    float4 a = *(const float4*)(x + i);
    float4 b = *(const float4*)(x + i + 4);
    *(uint4*)(xb + i) = make_uint4(pk2(a.x, a.y), pk2(a.z, a.w), pk2(b.x, b.y), pk2(b.z, b.w));
}

// ---------------- head GEMMs ----------------
// 64x64 tile, 4x4 micro-tile, register double-buffer of the next global tile
// (hides cold-HBM A latency under the 256-FMA compute phase).

#define GEMM_COMPUTE_16()                                                      \
    _Pragma("unroll")                                                          \
    for (int k = 0; k < 16; ++k) {                                             \
        float4 a4 = *(const float4*)&As[k][ty * 4];                            \
        float4 b4 = *(const float4*)&Bs[k][tx * 4];                            \
        acc[0][0] = fmaf(a4.x, b4.x, acc[0][0]);                               \
        acc[0][1] = fmaf(a4.x, b4.y, acc[0][1]);                               \
        acc[0][2] = fmaf(a4.x, b4.z, acc[0][2]);                               \
        acc[0][3] = fmaf(a4.x, b4.w, acc[0][3]);                               \
        acc[1][0] = fmaf(a4.y, b4.x, acc[1][0]);                               \
        acc[1][1] = fmaf(a4.y, b4.y, acc[1][1]);                               \
        acc[1][2] = fmaf(a4.y, b4.z, acc[1][2]);                               \
        acc[1][3] = fmaf(a4.y, b4.w, acc[1][3]);                               \
        acc[2][0] = fmaf(a4.z, b4.x, acc[2][0]);                               \
        acc[2][1] = fmaf(a4.z, b4.y, acc[2][1]);                               \
        acc[2][2] = fmaf(a4.z, b4.z, acc[2][2]);                               \
        acc[2][3] = fmaf(a4.z, b4.w, acc[2][3]);                               \
        acc[3][0] = fmaf(a4.w, b4.x, acc[3][0]);                               \
        acc[3][1] = fmaf(a4.w, b4.y, acc[3][1]);                               \
        acc[3][2] = fmaf(a4.w, b4.z, acc[3][2]);                               \
        acc[3][3] = fmaf(a4.w, b4.w, acc[3][3]);                               \
    }

// Fused (single K pass): C = act(A@B + bias), C uses ldc.
__global__ __launch_bounds__(256) void k_gemm_f(const float* __restrict__ A, const float* __restrict__ B,
                                                const float* __restrict__ bias, float* __restrict__ C,
                                                int Nc, int K, int ldc, int do_relu) {
    __shared__ float As[16][64];
    __shared__ float Bs[16][64];
    int tid = threadIdx.x;
    int tx = tid & 15, ty = tid >> 4;
    int bm = blockIdx.x * 64, bn = blockIdx.y * 64;
    float acc[4][4] = {{0.f}};
    int am = tid >> 2;
    int ak = (tid & 3) * 4;
    int bk = tid >> 4;
    int bn4 = (tid & 15) * 4;
    const float* Ap = A + (size_t)(bm + am) * K + ak;
    const float* Bp = B + (size_t)bk * Nc + bn + bn4;
    float4 av = *(const float4*)Ap;
    float4 bv = *(const float4*)Bp;
    for (int k0 = 0; k0 < K; k0 += 16) {
        As[ak + 0][am] = av.x;
        As[ak + 1][am] = av.y;
        As[ak + 2][am] = av.z;
        As[ak + 3][am] = av.w;
        *(float4*)&Bs[bk][bn4] = bv;
        __syncthreads();
        if (k0 + 16 < K) {
            av = *(const float4*)(Ap + k0 + 16);
            bv = *(const float4*)(Bp + (size_t)(k0 + 16) * Nc);
        }
        GEMM_COMPUTE_16()
        __syncthreads();
    }
    float4 bi = *(const float4*)(bias + bn + tx * 4);
#pragma unroll
    for (int i = 0; i < 4; ++i) {
        float4 v;
        v.x = acc[i][0] + bi.x;
        v.y = acc[i][1] + bi.y;
        v.z = acc[i][2] + bi.z;
        v.w = acc[i][3] + bi.w;
        if (do_relu) {
            v.x = fmaxf(v.x, 0.f); v.y = fmaxf(v.y, 0.f);
            v.z = fmaxf(v.z, 0.f); v.w = fmaxf(v.w, 0.f);
        }
        *(float4*)(C + (size_t)(bm + ty * 4 + i) * ldc + bn + tx * 4) = v;
    }
}

// K-split partial: slice z covers k in [z*klen, (z+1)*klen), writes psum slice.
__global__ __launch_bounds__(256) void k_gemm_p(const float* __restrict__ A, const float* __restrict__ B,
                                                float* __restrict__ psum, int Nc, int Ktot, int klen) {
    __shared__ float As[16][64];
    __shared__ float Bs[16][64];
    int tid = threadIdx.x;
    int tx = tid & 15, ty = tid >> 4;
    int bm = blockIdx.x * 64, bn = blockIdx.y * 64;
    int kb = blockIdx.z * klen;
    float acc[4][4] = {{0.f}};
    int am = tid >> 2;
    int ak = (tid & 3) * 4;
    int bk = tid >> 4;
    int bn4 = (tid & 15) * 4;
    const float* Ap = A + (size_t)(bm + am) * Ktot + kb + ak;
    const float* Bp = B + (size_t)(kb + bk) * Nc + bn + bn4;
    float4 av = *(const float4*)Ap;
    float4 bv = *(const float4*)Bp;
    for (int k0 = 0; k0 < klen; k0 += 16) {
        As[ak + 0][am] = av.x;
        As[ak + 1][am] = av.y;
        As[ak + 2][am] = av.z;
        As[ak + 3][am] = av.w;
        *(float4*)&Bs[bk][bn4] = bv;
        __syncthreads();
        if (k0 + 16 < klen) {
            av = *(const float4*)(Ap + k0 + 16);
            bv = *(const float4*)(Bp + (size_t)(k0 + 16) * Nc);
        }
        GEMM_COMPUTE_16()
        __syncthreads();
    }
    float* out = psum + (size_t)blockIdx.z * N_GRAPH * Nc;
#pragma unroll
    for (int i = 0; i < 4; ++i) {
        float4 v = make_float4(acc[i][0], acc[i][1], acc[i][2], acc[i][3]);
        *(float4*)(out + (size_t)(bm + ty * 4 + i) * Nc + bn + tx * 4) = v;
    }
}

// Sum S psum slices + bias (+relu) -> C (with ldc/offset folded into C).
__global__ __launch_bounds__(256) void k_reduce(const float* __restrict__ psum, const float* __restrict__ bias,
                                                float* __restrict__ C, int S, int Nc, int ldc, int do_relu) {
    int idx = blockIdx.x * 256 + threadIdx.x;
    int nq = Nc >> 2;
    if (idx >= N_GRAPH * nq) return;
    int m = idx / nq;
    int j = (idx - m * nq) * 4;
    float4 s = *(const float4*)(psum + (size_t)m * Nc + j);
    for (int z = 1; z < S; ++z) {
        float4 t = *(const float4*)(psum + (size_t)z * N_GRAPH * Nc + (size_t)m * Nc + j);
        s.x += t.x; s.y += t.y; s.z += t.z; s.w += t.w;
    }
    float4 bi = *(const float4*)(bias + j);
    s.x += bi.x; s.y += bi.y; s.z += bi.z; s.w += bi.w;
    if (do_relu) {
        s.x = fmaxf(s.x, 0.f); s.y = fmaxf(s.y, 0.f);
        s.z = fmaxf(s.z, 0.f); s.w = fmaxf(s.w, 0.f);
    }
    *(float4*)(C + (size_t)m * ldc + j) = s;
}

// ---------------- final dot ----------------

__global__ __launch_bounds__(256) void k_out(const float* __restrict__ z2, const float* __restrict__ w,
                                             const float* __restrict__ b, float* __restrict__ out) {
    int gid = blockIdx.x * 256 + threadIdx.x;
    int g = gid >> 6;
    int lane = threadIdx.x & 63;
    if (g >= N_GRAPH) return;
    float4 a = *(const float4*)(z2 + (size_t)g * 256 + lane * 4);
    float4 wv = *(const float4*)(w + lane * 4);
    float v = a.x * wv.x + a.y * wv.y + a.z * wv.z + a.w * wv.w;
#pragma unroll
    for (int off = 32; off > 0; off >>= 1) v += __shfl_down(v, off);
    if (lane == 0) out[g] = v + b[0];
}

// ---------------- launcher ----------------

extern "C" void kernel_launch(void* const* d_in, const int* in_sizes, int n_in,
                              void* d_out, int out_size, void* d_ws, size_t ws_size,
                              hipStream_t stream) {
    const float* x     = (const float*)d_in[0];
    const int*   eidx  = (const int*)d_in[1];
    const int*   batch = (const int*)d_in[2];
    const float* sf    = (const float*)d_in[3];
    const float* w1a   = (const float*)d_in[4];
    const float* b1a   = (const float*)d_in[5];
    const float* ws_a  = (const float*)d_in[6];
    const float* bs_a  = (const float*)d_in[7];
    const float* ws_b  = (const float*)d_in[8];
    const float* bs_b  = (const float*)d_in[9];
    const float* bn_g  = (const float*)d_in[10];
    const float* bn_b  = (const float*)d_in[11];
    const float* fcg_w = (const float*)d_in[12];
    const float* fcg_b = (const float*)d_in[13];
    const float* fs1_w = (const float*)d_in[14];
    const float* fs1_b = (const float*)d_in[15];
    const float* fs2_w = (const float*)d_in[16];
    const float* fs2_b = (const float*)d_in[17];
    const float* fc1_w = (const float*)d_in[18];
    const float* fc1_b = (const float*)d_in[19];
    const float* fc2_w = (const float*)d_in[20];
    const float* fc2_b = (const float*)d_in[21];
    const float* out_w = (const float*)d_in[22];
    const float* out_b = (const float*)d_in[23];
    float* dout = (float*)d_out;

    char* p = (char*)d_ws;
    float*  agg     = (float*)p;  p += (size_t)N_NODES * 64 * 4;   // 25.6 MB
    ushort* ubuf    = (ushort*)p; p += (size_t)N_NODES * 32 * 2;   // 6.4 MB
    int*    ssrc    = (int*)p;    p += (size_t)N_EDGES * 4;        // 6.4 MB
    int*    row_ptr = (int*)p;    p += (size_t)N_NODES * 4;
    int*    cursor  = (int*)p;    p += (size_t)N_NODES * 4;
    int*    part    = (int*)p;    p += 512 * 4;
    int*    deg     = (int*)p;    p += (size_t)N_NODES * 4;        // zero start
    float*  stats   = (float*)p;  p += 320 * 4;
    float*  pooled  = (float*)p;  p += (size_t)N_GRAPH * 32 * 4;   // zero end
    ushort* xb      = (ushort*)p; p += (size_t)N_NODES * 64 * 2;   // 12.8 MB (optional)
    bool use_xb = ((size_t)(p - (char*)d_ws) <= ws_size);

    // head buffers alias agg (25.6 MB region, dead by head time): 22 MB used
    float* zcat  = agg;                   // 2048*256   (2 MB)  [gfeat | s2]
    float* z1buf = zcat + 2048 * 256;     // 2048*1024  (8 MB)
    float* z2buf = z1buf + 2048 * 1024;   // 2048*256   (2 MB)
    float* s1buf = z2buf + 2048 * 256;    // 2048*256   (2 MB)
    float* psum  = s1buf + 2048 * 256;    // up to 4*2048*256 (8 MB)

    size_t zero_bytes = ((size_t)N_NODES + 320 + (size_t)N_GRAPH * 32) * 4;
    hipMemsetAsync(deg, 0, zero_bytes, stream);

    const int* esrc = eidx;
    const int* edst = eidx + N_EDGES;
    int nb = (N_NODES + 1023) / 1024;  // 98

    k_hist<<<N_EDGES / 256, 256, 0, stream>>>(edst, deg);
    k_scan_partial<<<nb, 256, 0, stream>>>(deg, part);
    k_scan_offsets<<<1, 256, 0, stream>>>(part, nb);
    k_scan_final<<<nb, 256, 0, stream>>>(deg, part, row_ptr, cursor);
    for (int k = 0; k < 5; ++k) {
        int lo = k * 20000;
        int hi = (k == 4) ? N_NODES : lo + 20000;
        k_scatter_pass<<<N_EDGES / 256, 256, 0, stream>>>(esrc, edst, cursor, ssrc, lo, hi);
    }

    // layer 1
    if (use_xb) {
        k_cvt_bf16<<<(N_NODES * 64 / 8 + 255) / 256, 256, 0, stream>>>(x, xb, N_NODES * 64);
        k_gather64b<<<(N_NODES * 8) / 256, 256, 0, stream>>>(xb, row_ptr, cursor, ssrc, agg);
    } else {
        k_gather64<<<(N_NODES * 16) / 256, 256, 0, stream>>>(x, row_ptr, cursor, ssrc, agg);
    }
    k_mlp_stats<64><<<(N_NODES + 255) / 256, 256, 0, stream>>>(agg, w1a, b1a, ws_b, bs_b, ubuf, stats);
    // layers 2-5
    for (int L = 1; L <= 4; ++L) {
        k_gather_bn_b<<<(N_NODES * 4 + 255) / 256, 256, 0, stream>>>(
            ubuf, stats + (L - 1) * 64, bn_g + (L - 1) * 32, bn_b + (L - 1) * 32,
            row_ptr, cursor, ssrc, agg);
        k_mlp_stats<32><<<(N_NODES + 255) / 256, 256, 0, stream>>>(
            agg, ws_a + (size_t)(L - 1) * 1024, bs_a + (L - 1) * 32,
            ws_b + (size_t)L * 1024, bs_b + L * 32, ubuf, stats + L * 64);
    }
    // layer-5 BN + pooling
    {
        int waves = (N_NODES + 127) / 128;
        int blocks = (waves + 3) / 4;
        k_bn_pool<<<blocks, 256, 0, stream>>>(ubuf, stats + 256, bn_g + 128, bn_b + 128, batch, pooled);
    }

    // head
    k_gemm_f<<<dim3(32, 2), 256, 0, stream>>>(pooled, fcg_w, fcg_b, zcat, 128, 32, 256, 1);     // gfeat -> z[:, :128]
    k_gemm_p<<<dim3(32, 4, 4), 256, 0, stream>>>(sf, fs1_w, psum, 256, 512, 128);               // fs1 partials
    k_reduce<<<512, 256, 0, stream>>>(psum, fs1_b, s1buf, 4, 256, 256, 1);
    k_gemm_p<<<dim3(32, 2, 4), 256, 0, stream>>>(s1buf, fs2_w, psum, 128, 256, 64);             // fs2 partials
    k_reduce<<<256, 256, 0, stream>>>(psum, fs2_b, zcat + 128, 4, 128, 256, 1);                 // -> z[:, 128:]
    k_gemm_f<<<dim3(32, 16), 256, 0, stream>>>(zcat, fc1_w, fc1_b, z1buf, 1024, 256, 1024, 1);  // fc1
    k_gemm_p<<<dim3(32, 4, 4), 256, 0, stream>>>(z1buf, fc2_w, psum, 256, 1024, 256);           // fc2 partials
    k_reduce<<<512, 256, 0, stream>>>(psum, fc2_b, z2buf, 4, 256, 256, 1);
    k_out<<<512, 256, 0, stream>>>(z2buf, out_w, out_b, dout);
}